// Round 1
// baseline (3603.672 us; speedup 1.0000x reference)
//
#include <hip/hip_runtime.h>
#include <stdint.h>

typedef __bf16 bf16;
typedef __bf16 bf16x4 __attribute__((ext_vector_type(4)));
typedef __bf16 bf16x8 __attribute__((ext_vector_type(8)));
typedef float f32x4 __attribute__((ext_vector_type(4)));

#define MFMA16x16x32(A, B, C) __builtin_amdgcn_mfma_f32_16x16x32_bf16((A), (B), (C), 0, 0, 0)

#define B_ 512
#define T_ 100
#define F_ 1024
#define H_ 1024
#define TC_ 10  // T-chunk

__device__ __forceinline__ float sigmoid_f(float x) { return 1.0f / (1.0f + __expf(-x)); }
__device__ __forceinline__ float b2bsqrt_f(float x) {
  float s = sqrtf(1.0f + fabsf(x)) - 1.0f;
  return x >= 0.0f ? s : -s;
}

// async global->LDS, 16B per lane; LDS dest = wave-uniform base + lane*16
__device__ __forceinline__ void glds16(const void* g, void* l) {
  __builtin_amdgcn_global_load_lds((const __attribute__((address_space(1))) void*)g,
                                   (__attribute__((address_space(3))) void*)l, 16, 0, 0);
}

// ---------------- zero-init h slot 0, c state, barrier counters ----------------
__global__ __launch_bounds__(256) void zero_init(bf16* __restrict__ h0,
                                                 float* __restrict__ c0,
                                                 unsigned* __restrict__ bars, int n) {
  int i = blockIdx.x * blockDim.x + threadIdx.x;
  if (i < n) { h0[i] = (bf16)0.0f; c0[i] = 0.0f; }
  if (i < 16) bars[i] = 0u;
}

// ---------- transpose per gate: fp32 (1024 x 1024) -> bf16 transposed ----------
__global__ __launch_bounds__(256) void tr_kernel(const float* __restrict__ src,
                                                 bf16* __restrict__ dst) {
  __shared__ float tile[32][33];
  int g = blockIdx.z;
  int c0 = blockIdx.x * 32;
  int r0 = blockIdx.y * 32;
  const float* s = src + (size_t)g * 1024 * 1024;
  bf16* d = dst + (size_t)g * 1024 * 1024;
  int tx = threadIdx.x & 31, ty = threadIdx.x >> 5;
  #pragma unroll
  for (int i = 0; i < 32; i += 8)
    tile[ty + i][tx] = s[(size_t)(r0 + ty + i) * 1024 + c0 + tx];
  __syncthreads();
  #pragma unroll
  for (int i = 0; i < 32; i += 8)
    d[(size_t)(c0 + ty + i) * 1024 + r0 + tx] = (bf16)tile[tx][ty + i];
}

// ---------- convert x chunk fp32 -> bf16 ----------
__global__ __launch_bounds__(256) void convx(const float* __restrict__ x,
                                             bf16* __restrict__ xbf, int t0) {
  int lr = blockIdx.x * 4 + (threadIdx.x >> 6);
  int lane = threadIdx.x & 63;
  unsigned b = (unsigned)lr / 10u;
  unsigned tt = (unsigned)lr - b * 10u;
  const float* src = x + (size_t)(b * 100u + (unsigned)t0 + tt) * 1024;
  bf16* dst = xbf + (size_t)lr * 1024;
  #pragma unroll
  for (int j = 0; j < 4; ++j) {
    f32x4 f = *(const f32x4*)(src + (j * 64 + lane) * 4);
    bf16x4 o;
    o[0] = (bf16)f[0]; o[1] = (bf16)f[1]; o[2] = (bf16)f[2]; o[3] = (bf16)f[3];
    *(bf16x4*)(dst + (j * 64 + lane) * 4) = o;
  }
}

// ---------- prep FC (unchanged) ----------
__global__ __launch_bounds__(256) void prep_fc(const float* __restrict__ lng,
                                               const float* __restrict__ lnb,
                                               const float* __restrict__ fcw,
                                               const float* __restrict__ fcb,
                                               bf16* __restrict__ Bt,
                                               float* __restrict__ SA) {
  __shared__ float red[2][256];
  int c = blockIdx.x;
  int tid = threadIdx.x;
  float pS = 0.f, pA = 0.f;
  #pragma unroll
  for (int j = 0; j < 4; ++j) {
    int h = j * 256 + tid;
    float v;
    if (c < 10) {
      float wv = fcw[h * 10 + c];
      v = lng[h] * wv;
      pS += v;
      pA += lnb[h] * wv;
    } else {
      v = (c == 10) ? 1.0f : 0.0f;
    }
    Bt[c * 1024 + h] = (bf16)v;
  }
  if (c < 10) {
    red[0][tid] = pS; red[1][tid] = pA;
    __syncthreads();
    for (int s = 128; s > 0; s >>= 1) {
      if (tid < s) { red[0][tid] += red[0][tid + s]; red[1][tid] += red[1][tid + s]; }
      __syncthreads();
    }
    if (tid == 0) { SA[c] = red[0][0]; SA[16 + c] = red[1][0] + fcb[c]; }
  }
}

// ---------------- xz chunk GEMM (m97-style, unchanged) ----------------
__global__ __launch_bounds__(256) void gemm_xz(const bf16* __restrict__ X,
                                               const bf16* __restrict__ Wt,
                                               bf16* __restrict__ XZc) {
  __shared__ bf16 sA[128 * 32];
  __shared__ bf16 sB[128 * 32];
  const int tid = threadIdx.x;
  const int lane = tid & 63;
  const int w = tid >> 6;
  const int l16 = lane & 15;
  const int quad = lane >> 4;
  const int m0 = blockIdx.y * 128;
  const int n0 = blockIdx.x * 128;
  const int wm = (w >> 1) * 64;
  const int wn = (w & 1) * 64;
  const int rA = lane >> 2;
  const int gch = (lane & 3) ^ (rA & 3);

  f32x4 acc[4][4] = {};

  for (int kk = 0; kk < 1024; kk += 32) {
    #pragma unroll
    for (int j = 0; j < 2; ++j) {
      int r0 = (w * 2 + j) * 16;
      int r = r0 + rA;
      glds16(X + (size_t)(m0 + r) * 1024 + kk + gch * 8, sA + r0 * 32);
      glds16(Wt + (size_t)(n0 + r) * 1024 + kk + gch * 8, sB + r0 * 32);
    }
    __syncthreads();
    bf16x8 aF[4], bF[4];
    const int slot = quad ^ (l16 & 3);
    #pragma unroll
    for (int mt = 0; mt < 4; ++mt)
      aF[mt] = *(const bf16x8*)(sA + (wm + mt * 16 + l16) * 32 + slot * 8);
    #pragma unroll
    for (int nt = 0; nt < 4; ++nt)
      bF[nt] = *(const bf16x8*)(sB + (wn + nt * 16 + l16) * 32 + slot * 8);
    #pragma unroll
    for (int mt = 0; mt < 4; ++mt)
      #pragma unroll
      for (int nt = 0; nt < 4; ++nt)
        acc[mt][nt] = MFMA16x16x32(aF[mt], bF[nt], acc[mt][nt]);
    __syncthreads();
  }

  #pragma unroll
  for (int mt = 0; mt < 4; ++mt) {
    #pragma unroll
    for (int r = 0; r < 4; ++r) {
      unsigned lr = (unsigned)(m0 + wm + mt * 16 + quad * 4 + r);
      unsigned b = lr / 10u;
      unsigned tt = lr - b * 10u;
      #pragma unroll
      for (int nt = 0; nt < 4; ++nt) {
        int n = n0 + wn + nt * 16 + l16;
        int g = n >> 10;
        int hh = n & 1023;
        XZc[((size_t)(tt * 4 + g) * B_ + b) * H_ + hh] = (bf16)acc[mt][nt][r];
      }
    }
  }
}

// ------------- persistent recurrence: TC_ steps per launch, grid barrier between -------------
// grid (32, 8) = 256 blocks == #CUs; LDS 84KB forces 1 block/CU => all co-resident.
// Block tile: M=64 (b), N=128 (4 gates x 32 h). Wave w = gate w, nt in {0,1} -> 32 n-cols/wave.
// Ut B-fragments persist in VGPRs (256 regs) for the whole launch; c-state persists in regs.
// K-loop: BK=128, double-buffered global_load_lds with counted s_waitcnt vmcnt(4) + raw barriers.
__global__ __launch_bounds__(256, 1) void step_persist(
    int t0,
    const bf16* __restrict__ XZc,    // (TC,4,B,H) bf16
    const bf16* __restrict__ Ut,     // (4096,1024): row n=g*1024+h, col k
    const float* __restrict__ bias,  // (4,H)
    bf16* __restrict__ hseq,         // slots t0..t0+TC
    float* __restrict__ cst,         // (B,H) fp32 (load at start, store at end)
    unsigned* __restrict__ bar) {    // this launch's arrival counter
  __shared__ bf16 sA[2][64 * 128];   // 32 KB: A tile double-buffer
  __shared__ float sZ[4][64 * 52];   // 52 KB: Z dump (stride 52 -> 16B aligned, bank spread)

  const int tid = threadIdx.x;
  const int lane = tid & 63;
  const int w = tid >> 6;            // wave = gate id
  const int l16 = lane & 15;
  const int quad = lane >> 4;
  const int hn0 = blockIdx.x * 32;
  const int bm0 = blockIdx.y * 64;

  // ---- persistent B fragments: bfr[nt][ks] = Ut[w*1024 + hn0 + nt*16 + l16][ks*32 + quad*8 ..+8]
  bf16x8 bfr[2][32];
  #pragma unroll
  for (int nt = 0; nt < 2; ++nt) {
    const bf16* up = Ut + (size_t)((w << 10) + hn0 + nt * 16 + l16) * 1024 + quad * 8;
    #pragma unroll
    for (int ks = 0; ks < 32; ++ks)
      bfr[nt][ks] = *(const bf16x8*)(up + ks * 32);
  }

  // ---- gate-phase mapping: row rr (0..63), 8 h-cols at cc; persistent c-state + bias
  const int rr = tid >> 2;
  const int cc = (tid & 3) * 8;
  const int gb = bm0 + rr;
  const int gh = hn0 + cc;
  f32x4 creg[2];
  creg[0] = *(const f32x4*)(cst + (size_t)gb * H_ + gh);
  creg[1] = *(const f32x4*)(cst + (size_t)gb * H_ + gh + 4);
  f32x4 bs[4][2];
  #pragma unroll
  for (int g = 0; g < 4; ++g) {
    bs[g][0] = *(const f32x4*)(bias + g * H_ + gh);
    bs[g][1] = *(const f32x4*)(bias + g * H_ + gh + 4);
  }

  // staging geometry: round j stages rows j*16..j*16+16 (16 rows x 256B = 4KB = 256 lanes x 16B)
  const int srow = tid >> 4;             // 0..15 = row within round = (row & 15)
  const int gch = (tid & 15) ^ srow;     // pre-swizzled global 16B chunk (involution)
  const int ldsw = (w << 2) * 128;       // wave's LDS row base within a round (elems)

  unsigned target = 0;

  for (int tt = 0; tt < TC_; ++tt) {
    const bf16* hp = hseq + (size_t)(t0 + tt) * B_ * H_;
    bf16* hnx = hseq + (size_t)(t0 + tt + 1) * B_ * H_;

    // prefetch xz for the gate phase (in-order vmem retirement keeps counted waits safe)
    bf16x8 xzv[4];
    #pragma unroll
    for (int g = 0; g < 4; ++g)
      xzv[g] = *(const bf16x8*)(XZc + ((size_t)(tt * 4 + g) * B_ + gb) * H_ + gh);

    f32x4 acc[4][2] = {};

    // prologue: stage K-tile 0 -> buf 0 (4 glds16 per thread)
    #pragma unroll
    for (int j = 0; j < 4; ++j)
      glds16(hp + (size_t)(bm0 + j * 16 + srow) * H_ + gch * 8,
             &sA[0][j * 16 * 128 + ldsw]);

    #pragma unroll
    for (int t = 0; t < 8; ++t) {
      const int cur = t & 1;
      if (t < 7) {
        const int kk = (t + 1) * 128;
        #pragma unroll
        for (int j = 0; j < 4; ++j)
          glds16(hp + (size_t)(bm0 + j * 16 + srow) * H_ + kk + gch * 8,
                 &sA[cur ^ 1][j * 16 * 128 + ldsw]);
        asm volatile("s_waitcnt vmcnt(4)" ::: "memory");  // tile t landed; t+1 stays in flight
      } else {
        asm volatile("s_waitcnt vmcnt(0)" ::: "memory");
      }
      __builtin_amdgcn_sched_barrier(0);
      __builtin_amdgcn_s_barrier();          // everyone's tile-t loads landed
      __builtin_amdgcn_sched_barrier(0);
      #pragma unroll
      for (int kh = 0; kh < 4; ++kh) {
        bf16x8 aF[4];
        #pragma unroll
        for (int mt = 0; mt < 4; ++mt) {
          const int R = mt * 16 + l16;
          aF[mt] = *(const bf16x8*)(&sA[cur][R * 128 + (((kh * 4 + quad) ^ l16) * 8)]);
        }
        #pragma unroll
        for (int mt = 0; mt < 4; ++mt) {
          acc[mt][0] = MFMA16x16x32(aF[mt], bfr[0][t * 4 + kh], acc[mt][0]);
          acc[mt][1] = MFMA16x16x32(aF[mt], bfr[1][t * 4 + kh], acc[mt][1]);
        }
      }
      __builtin_amdgcn_sched_barrier(0);
      __builtin_amdgcn_s_barrier();          // all done reading buf[cur]; safe to overwrite next iter
    }

    // Z dump (C/D layout: row=quad*4+r, col=l16), per-wave gate w, 2 n-tiles
    #pragma unroll
    for (int mt = 0; mt < 4; ++mt)
      #pragma unroll
      for (int nt = 0; nt < 2; ++nt)
        #pragma unroll
        for (int r = 0; r < 4; ++r)
          sZ[w][(mt * 16 + quad * 4 + r) * 52 + nt * 16 + l16] = acc[mt][nt][r];
    __syncthreads();

    // gates: 8 h per thread
    bf16x8 hb;
    #pragma unroll
    for (int p = 0; p < 2; ++p) {
      f32x4 z0 = *(const f32x4*)(&sZ[0][rr * 52 + cc + p * 4]);
      f32x4 z1 = *(const f32x4*)(&sZ[1][rr * 52 + cc + p * 4]);
      f32x4 z2 = *(const f32x4*)(&sZ[2][rr * 52 + cc + p * 4]);
      f32x4 z3 = *(const f32x4*)(&sZ[3][rr * 52 + cc + p * 4]);
      #pragma unroll
      for (int jj = 0; jj < 4; ++jj) {
        const int e = p * 4 + jj;
        float I  = sigmoid_f(z0[jj] + (float)xzv[0][e] + bs[0][p][jj]);
        float Fg = sigmoid_f(z1[jj] + (float)xzv[1][e] + bs[1][p][jj]);
        float O  = sigmoid_f(z2[jj] + (float)xzv[2][e] + bs[2][p][jj]);
        float Ct = b2bsqrt_f(z3[jj] + (float)xzv[3][e] + bs[3][p][jj]);
        float c2 = Fg * creg[p][jj] + I * Ct;
        creg[p][jj] = c2;
        hb[e] = (bf16)(O * b2bsqrt_f(c2));
      }
    }
    *(bf16x8*)(hnx + (size_t)gb * H_ + gh) = hb;

    // ---- device-scope grid barrier (skip after last step) ----
    if (tt < TC_ - 1) {
      target += 256;
      __syncthreads();                        // drains vmcnt(0): hnx stores reached L2
      if (tid == 0) {
        __threadfence();                      // agent release: L2 writeback
        atomicAdd(bar, 1u);
        unsigned spins = 0;
        while (__hip_atomic_load(bar, __ATOMIC_RELAXED, __HIP_MEMORY_SCOPE_AGENT) < target) {
          __builtin_amdgcn_s_sleep(2);
          if (++spins > (1u << 20)) break;    // bounded: fail loud, never hang the harness
        }
        __threadfence();                      // agent acquire: invalidate L1/L2
      }
      __syncthreads();
    }
  }

  // write back persistent c-state for the next chunk's launch
  *(f32x4*)(cst + (size_t)gb * H_ + gh) = creg[0];
  *(f32x4*)(cst + (size_t)gb * H_ + gh + 4) = creg[1];
}

// ------------- LN+FC as MFMA GEMM (unchanged) -------------
__global__ __launch_bounds__(256) void ln_fc_kernel(
    const bf16* __restrict__ hseq1, const bf16* __restrict__ Bt,
    const float* __restrict__ SA, float* __restrict__ out) {
  __shared__ bf16 sA[64 * 64];
  __shared__ bf16 sBt[16 * 1040];
  __shared__ float sLg[4][16 * 17];
  __shared__ float sSq[4][16];
  const int tid = threadIdx.x;
  const int lane = tid & 63;
  const int w = tid >> 6;
  const int l16 = lane & 15;
  const int quad = lane >> 4;
  const int m0 = blockIdx.x * 64;
  const int rL = lane >> 3;
  const int gch = (lane & 7) ^ rL;

  #pragma unroll
  for (int i = 0; i < 8; ++i) {
    int ch = tid + i * 256;
    int n = ch >> 7, k8 = ch & 127;
    *(bf16x8*)(sBt + n * 1040 + k8 * 8) = *(const bf16x8*)(Bt + n * 1024 + k8 * 8);
  }

  f32x4 acc = {};
  float sq = 0.f;

  for (int kk = 0; kk < 1024; kk += 64) {
    #pragma unroll
    for (int j = 0; j < 2; ++j) {
      int r0 = (w * 2 + j) * 8;
      int r = r0 + rL;
      glds16(hseq1 + (size_t)(m0 + r) * 1024 + kk + gch * 8, sA + r0 * 64);
    }
    __syncthreads();
    #pragma unroll
    for (int kh = 0; kh < 2; ++kh) {
      const int slot = (kh * 4 + quad) ^ (l16 & 7);
      bf16x8 aF = *(const bf16x8*)(sA + (w * 16 + l16) * 64 + slot * 8);
      bf16x8 bF = *(const bf16x8*)(sBt + l16 * 1040 + kk + kh * 32 + quad * 8);
      acc = MFMA16x16x32(aF, bF, acc);
      #pragma unroll
      for (int e = 0; e < 8; ++e) { float f = (float)aF[e]; sq += f * f; }
    }
    __syncthreads();
  }

  sq += __shfl_xor(sq, 16, 64);
  sq += __shfl_xor(sq, 32, 64);

  #pragma unroll
  for (int r = 0; r < 4; ++r)
    sLg[w][(quad * 4 + r) * 17 + l16] = acc[r];
  if (quad == 0) sSq[w][l16] = sq;
  __syncthreads();

  if (lane < 16) {
    int row = lane;
    float sum = sLg[w][row * 17 + 10];
    float ssq = sSq[w][row];
    float mu = sum * (1.0f / 1024.0f);
    float var = ssq * (1.0f / 1024.0f) - mu * mu;
    float rs = rsqrtf(var + 1e-5f);
    int rg = m0 + w * 16 + row;
    int t = rg >> 9, b = rg & 511;
    float* op = out + ((size_t)b * 100 + t) * 10;
    #pragma unroll
    for (int c = 0; c < 10; ++c)
      op[c] = rs * (sLg[w][row * 17 + c] - mu * SA[c]) + SA[16 + c];
  }
}

extern "C" void kernel_launch(void* const* d_in, const int* in_sizes, int n_in,
                              void* d_out, int out_size, void* d_ws, size_t ws_size,
                              hipStream_t stream) {
  (void)in_sizes; (void)n_in; (void)out_size; (void)ws_size;
  const float* x    = (const float*)d_in[0];
  const float* W    = (const float*)d_in[1];
  const float* U    = (const float*)d_in[2];
  const float* bias = (const float*)d_in[3];
  const float* lng  = (const float*)d_in[4];
  const float* lnb  = (const float*)d_in[5];
  const float* fcw  = (const float*)d_in[6];
  const float* fcb  = (const float*)d_in[7];
  float* out = (float*)d_out;

  char* ws = (char*)d_ws;
  size_t off = 0;
  bf16* Wt   = (bf16*)(ws + off); off += (size_t)4 * F_ * H_ * 2;
  bf16* Ut   = (bf16*)(ws + off); off += (size_t)4 * H_ * H_ * 2;
  bf16* XZc  = (bf16*)(ws + off); off += (size_t)TC_ * 4 * B_ * H_ * 2;
  bf16* hseq = (bf16*)(ws + off); off += (size_t)(T_ + 1) * B_ * H_ * 2;
  float* cst = (float*)(ws + off); off += (size_t)B_ * H_ * 4;
  bf16* xbf  = (bf16*)(ws + off); off += (size_t)B_ * TC_ * F_ * 2;
  bf16* Bt   = (bf16*)(ws + off); off += (size_t)16 * H_ * 2;
  float* SA  = (float*)(ws + off); off += 32 * 4;
  unsigned* bars = (unsigned*)(ws + off); off += 16 * 4;

  zero_init<<<(B_ * H_ + 255) / 256, 256, 0, stream>>>(hseq, cst, bars, B_ * H_);
  tr_kernel<<<dim3(32, 32, 4), 256, 0, stream>>>(W, Wt);
  tr_kernel<<<dim3(32, 32, 4), 256, 0, stream>>>(U, Ut);
  prep_fc<<<16, 256, 0, stream>>>(lng, lnb, fcw, fcb, Bt, SA);

  for (int chunk = 0; chunk < T_ / TC_; ++chunk) {
    int t0 = chunk * TC_;
    convx<<<(B_ * TC_) / 4, 256, 0, stream>>>(x, xbf, t0);
    gemm_xz<<<dim3(32, (B_ * TC_) / 128), 256, 0, stream>>>(xbf, Wt, XZc);
    step_persist<<<dim3(32, 8), 256, 0, stream>>>(t0, XZc, Ut, bias, hseq, cst,
                                                  bars + chunk);
  }

  ln_fc_kernel<<<(B_ * T_) / 64, 256, 0, stream>>>(hseq + (size_t)B_ * H_, Bt, SA, out);
}

// Round 2
// 2662.695 us; speedup vs baseline: 1.3534x; 1.3534x over previous
//
#include <hip/hip_runtime.h>
#include <stdint.h>

typedef __bf16 bf16;
typedef __bf16 bf16x4 __attribute__((ext_vector_type(4)));
typedef __bf16 bf16x8 __attribute__((ext_vector_type(8)));
typedef float f32x4 __attribute__((ext_vector_type(4)));

#define MFMA16x16x32(A, B, C) __builtin_amdgcn_mfma_f32_16x16x32_bf16((A), (B), (C), 0, 0, 0)

#define B_ 512
#define T_ 100
#define F_ 1024
#define H_ 1024
#define TC_ 10  // T-chunk

__device__ __forceinline__ float sigmoid_f(float x) { return 1.0f / (1.0f + __expf(-x)); }
__device__ __forceinline__ float b2bsqrt_f(float x) {
  float s = sqrtf(1.0f + fabsf(x)) - 1.0f;
  return x >= 0.0f ? s : -s;
}

// async global->LDS, 16B per lane; LDS dest = wave-uniform base + lane*16
__device__ __forceinline__ void glds16(const void* g, void* l) {
  __builtin_amdgcn_global_load_lds((const __attribute__((address_space(1))) void*)g,
                                   (__attribute__((address_space(3))) void*)l, 16, 0, 0);
}

// ---------------- zero-init h slot 0, c state, barrier counters ----------------
__global__ __launch_bounds__(256) void zero_init(bf16* __restrict__ h0,
                                                 float* __restrict__ c0,
                                                 unsigned* __restrict__ bars, int n) {
  int i = blockIdx.x * blockDim.x + threadIdx.x;
  if (i < n) { h0[i] = (bf16)0.0f; c0[i] = 0.0f; }
  if (i < 10 * 1024) bars[i] = 0u;   // 10 chunks x 1024 dwords of barrier state
}

// ---------- transpose per gate: fp32 (1024 x 1024) -> bf16 transposed ----------
__global__ __launch_bounds__(256) void tr_kernel(const float* __restrict__ src,
                                                 bf16* __restrict__ dst) {
  __shared__ float tile[32][33];
  int g = blockIdx.z;
  int c0 = blockIdx.x * 32;
  int r0 = blockIdx.y * 32;
  const float* s = src + (size_t)g * 1024 * 1024;
  bf16* d = dst + (size_t)g * 1024 * 1024;
  int tx = threadIdx.x & 31, ty = threadIdx.x >> 5;
  #pragma unroll
  for (int i = 0; i < 32; i += 8)
    tile[ty + i][tx] = s[(size_t)(r0 + ty + i) * 1024 + c0 + tx];
  __syncthreads();
  #pragma unroll
  for (int i = 0; i < 32; i += 8)
    d[(size_t)(c0 + ty + i) * 1024 + r0 + tx] = (bf16)tile[tx][ty + i];
}

// ---------- convert x chunk fp32 -> bf16 ----------
__global__ __launch_bounds__(256) void convx(const float* __restrict__ x,
                                             bf16* __restrict__ xbf, int t0) {
  int lr = blockIdx.x * 4 + (threadIdx.x >> 6);
  int lane = threadIdx.x & 63;
  unsigned b = (unsigned)lr / 10u;
  unsigned tt = (unsigned)lr - b * 10u;
  const float* src = x + (size_t)(b * 100u + (unsigned)t0 + tt) * 1024;
  bf16* dst = xbf + (size_t)lr * 1024;
  #pragma unroll
  for (int j = 0; j < 4; ++j) {
    f32x4 f = *(const f32x4*)(src + (j * 64 + lane) * 4);
    bf16x4 o;
    o[0] = (bf16)f[0]; o[1] = (bf16)f[1]; o[2] = (bf16)f[2]; o[3] = (bf16)f[3];
    *(bf16x4*)(dst + (j * 64 + lane) * 4) = o;
  }
}

// ---------- prep FC (unchanged) ----------
__global__ __launch_bounds__(256) void prep_fc(const float* __restrict__ lng,
                                               const float* __restrict__ lnb,
                                               const float* __restrict__ fcw,
                                               const float* __restrict__ fcb,
                                               bf16* __restrict__ Bt,
                                               float* __restrict__ SA) {
  __shared__ float red[2][256];
  int c = blockIdx.x;
  int tid = threadIdx.x;
  float pS = 0.f, pA = 0.f;
  #pragma unroll
  for (int j = 0; j < 4; ++j) {
    int h = j * 256 + tid;
    float v;
    if (c < 10) {
      float wv = fcw[h * 10 + c];
      v = lng[h] * wv;
      pS += v;
      pA += lnb[h] * wv;
    } else {
      v = (c == 10) ? 1.0f : 0.0f;
    }
    Bt[c * 1024 + h] = (bf16)v;
  }
  if (c < 10) {
    red[0][tid] = pS; red[1][tid] = pA;
    __syncthreads();
    for (int s = 128; s > 0; s >>= 1) {
      if (tid < s) { red[0][tid] += red[0][tid + s]; red[1][tid] += red[1][tid + s]; }
      __syncthreads();
    }
    if (tid == 0) { SA[c] = red[0][0]; SA[16 + c] = red[1][0] + fcb[c]; }
  }
}

// ---------------- xz chunk GEMM (m97-style, unchanged) ----------------
__global__ __launch_bounds__(256) void gemm_xz(const bf16* __restrict__ X,
                                               const bf16* __restrict__ Wt,
                                               bf16* __restrict__ XZc) {
  __shared__ bf16 sA[128 * 32];
  __shared__ bf16 sB[128 * 32];
  const int tid = threadIdx.x;
  const int lane = tid & 63;
  const int w = tid >> 6;
  const int l16 = lane & 15;
  const int quad = lane >> 4;
  const int m0 = blockIdx.y * 128;
  const int n0 = blockIdx.x * 128;
  const int wm = (w >> 1) * 64;
  const int wn = (w & 1) * 64;
  const int rA = lane >> 2;
  const int gch = (lane & 3) ^ (rA & 3);

  f32x4 acc[4][4] = {};

  for (int kk = 0; kk < 1024; kk += 32) {
    #pragma unroll
    for (int j = 0; j < 2; ++j) {
      int r0 = (w * 2 + j) * 16;
      int r = r0 + rA;
      glds16(X + (size_t)(m0 + r) * 1024 + kk + gch * 8, sA + r0 * 32);
      glds16(Wt + (size_t)(n0 + r) * 1024 + kk + gch * 8, sB + r0 * 32);
    }
    __syncthreads();
    bf16x8 aF[4], bF[4];
    const int slot = quad ^ (l16 & 3);
    #pragma unroll
    for (int mt = 0; mt < 4; ++mt)
      aF[mt] = *(const bf16x8*)(sA + (wm + mt * 16 + l16) * 32 + slot * 8);
    #pragma unroll
    for (int nt = 0; nt < 4; ++nt)
      bF[nt] = *(const bf16x8*)(sB + (wn + nt * 16 + l16) * 32 + slot * 8);
    #pragma unroll
    for (int mt = 0; mt < 4; ++mt)
      #pragma unroll
      for (int nt = 0; nt < 4; ++nt)
        acc[mt][nt] = MFMA16x16x32(aF[mt], bF[nt], acc[mt][nt]);
    __syncthreads();
  }

  #pragma unroll
  for (int mt = 0; mt < 4; ++mt) {
    #pragma unroll
    for (int r = 0; r < 4; ++r) {
      unsigned lr = (unsigned)(m0 + wm + mt * 16 + quad * 4 + r);
      unsigned b = lr / 10u;
      unsigned tt = lr - b * 10u;
      #pragma unroll
      for (int nt = 0; nt < 4; ++nt) {
        int n = n0 + wn + nt * 16 + l16;
        int g = n >> 10;
        int hh = n & 1023;
        XZc[((size_t)(tt * 4 + g) * B_ + b) * H_ + hh] = (bf16)acc[mt][nt][r];
      }
    }
  }
}

// ------------- persistent recurrence v2: 512 thr (8 waves = 2/SIMD), K-split waves,
//               4-deep LDS pipeline (1 barrier/tile), hierarchical grid barrier -------------
// 1-D grid 256 blocks. bm = bid&7 (b tile, 64 rows), hn = bid>>3 (32 h-cols).
// The 32 blocks sharing a bm-tile are bid===bm (mod 8) -> same XCD under round-robin
// (performance-only locality; correctness uses agent-scope fences).
// Wave w: gate = w&3, K-half hf = w>>2 (k-slots hf*64..hf*64+64 of every 128-tile).
// Ut B-fragments persist in VGPRs (bfr[2][16] = 128 VGPR); c-state persists in regs.
__global__ __launch_bounds__(512, 2) void step_persist(
    int t0,
    const bf16* __restrict__ XZc,    // (TC,4,B,H) bf16
    const bf16* __restrict__ Ut,     // (4096,1024): row n=g*1024+h, col k
    const float* __restrict__ bias,  // (4,H)
    bf16* __restrict__ hseq,         // slots t0..t0+TC
    float* __restrict__ cst,         // (B,H) fp32
    unsigned* __restrict__ bar) {    // this chunk's barrier state (1024 dwords)
  __shared__ bf16 sA[4][64 * 128];   // 64 KB: A-tile quad-buffer (BK=128)
  __shared__ float sZ[8][64 * 36];   // 72 KB: per-wave partial Z (stride 36 = 16B aligned)

  const int tid = threadIdx.x;
  const int lane = tid & 63;
  const int w = tid >> 6;            // 0..7
  const int gate = w & 3;
  const int hf = w >> 2;             // K-half
  const int l16 = lane & 15;
  const int quad = lane >> 4;
  const int bid = blockIdx.x;
  const int bm0 = (bid & 7) * 64;
  const int hn0 = (bid >> 3) * 32;

  // ---- persistent B fragments: bfr[nt][t*2+kh] = Ut[gate*1024+hn0+nt*16+l16][t*128+hf*64+kh*32+quad*8 ..+8]
  bf16x8 bfr[2][16];
  #pragma unroll
  for (int nt = 0; nt < 2; ++nt) {
    const bf16* up = Ut + (size_t)((gate << 10) + hn0 + nt * 16 + l16) * 1024 + hf * 64 + quad * 8;
    #pragma unroll
    for (int t = 0; t < 8; ++t) {
      bfr[nt][t * 2 + 0] = *(const bf16x8*)(up + t * 128);
      bfr[nt][t * 2 + 1] = *(const bf16x8*)(up + t * 128 + 32);
    }
  }

  // ---- gate-phase mapping: 512 thr -> row rr (0..63) x 4 h-cols; persistent c-state
  const int rr = tid >> 3;
  const int cc = (tid & 7) * 4;
  const int gb = bm0 + rr;
  const int gh = hn0 + cc;
  f32x4 creg = *(const f32x4*)(cst + (size_t)gb * H_ + gh);

  // staging geometry: per tile 2 rounds x 32 rows; thread -> row j*32+(tid>>4), chunk tid&15
  const int srow = tid >> 4;               // 0..31
  const int gch = (tid & 15) ^ (srow & 15);  // XOR-swizzled global 16B chunk (involution)

  unsigned btarget = 0;

  for (int tt = 0; tt < TC_; ++tt) {
    const bf16* hp = hseq + (size_t)(t0 + tt) * B_ * H_;
    bf16* hnx = hseq + (size_t)(t0 + tt + 1) * B_ * H_;

    // prefetch gate-phase operands (oldest vmem ops; covered by counted waits below)
    bf16x4 xzv[4]; f32x4 bs[4];
    #pragma unroll
    for (int g = 0; g < 4; ++g) {
      xzv[g] = *(const bf16x4*)(XZc + ((size_t)(tt * 4 + g) * B_ + gb) * H_ + gh);
      bs[g] = *(const f32x4*)(bias + g * H_ + gh);
    }

    f32x4 acc[4][2] = {};

    // prologue: stage tiles 0,1
    #pragma unroll
    for (int pt = 0; pt < 2; ++pt)
      #pragma unroll
      for (int j = 0; j < 2; ++j)
        glds16(hp + (size_t)(bm0 + j * 32 + srow) * H_ + pt * 128 + gch * 8,
               &sA[pt][(j * 32 + w * 4) * 128]);

    #pragma unroll
    for (int t = 0; t < 8; ++t) {
      if (t < 6) {
        const int nb = (t + 2) & 3;
        #pragma unroll
        for (int j = 0; j < 2; ++j)
          glds16(hp + (size_t)(bm0 + j * 32 + srow) * H_ + (t + 2) * 128 + gch * 8,
                 &sA[nb][(j * 32 + w * 4) * 128]);
        asm volatile("s_waitcnt vmcnt(4)" ::: "memory");  // tile t landed; t+1,t+2 in flight
      } else if (t == 6) {
        asm volatile("s_waitcnt vmcnt(2)" ::: "memory");
      } else {
        asm volatile("s_waitcnt vmcnt(0)" ::: "memory");
      }
      __builtin_amdgcn_sched_barrier(0);
      __builtin_amdgcn_s_barrier();          // everyone's tile-t loads landed
      __builtin_amdgcn_sched_barrier(0);
      const int cur = t & 3;
      #pragma unroll
      for (int kh = 0; kh < 2; ++kh) {
        const int slot = ((hf * 2 + kh) * 4 + quad) ^ l16;
        bf16x8 aF[4];
        #pragma unroll
        for (int mt = 0; mt < 4; ++mt)
          aF[mt] = *(const bf16x8*)(&sA[cur][(mt * 16 + l16) * 128 + slot * 8]);
        #pragma unroll
        for (int mt = 0; mt < 4; ++mt) {
          acc[mt][0] = MFMA16x16x32(aF[mt], bfr[0][t * 2 + kh], acc[mt][0]);
          acc[mt][1] = MFMA16x16x32(aF[mt], bfr[1][t * 2 + kh], acc[mt][1]);
        }
      }
      __builtin_amdgcn_sched_barrier(0);
    }

    // partial-Z dump (C/D layout: row=quad*4+r, col=l16) to this wave's slab
    #pragma unroll
    for (int mt = 0; mt < 4; ++mt)
      #pragma unroll
      for (int nt = 0; nt < 2; ++nt)
        #pragma unroll
        for (int r = 0; r < 4; ++r)
          sZ[w][(mt * 16 + quad * 4 + r) * 36 + nt * 16 + l16] = acc[mt][nt][r];
    __syncthreads();

    // gates: 4 h per thread; z = half0 + half1
    bf16x4 hb;
    f32x4 z[4];
    #pragma unroll
    for (int g = 0; g < 4; ++g) {
      f32x4 za = *(const f32x4*)(&sZ[g][rr * 36 + cc]);
      f32x4 zb = *(const f32x4*)(&sZ[g + 4][rr * 36 + cc]);
      z[g] = za + zb;
    }
    #pragma unroll
    for (int jj = 0; jj < 4; ++jj) {
      float I  = sigmoid_f(z[0][jj] + (float)xzv[0][jj] + bs[0][jj]);
      float Fg = sigmoid_f(z[1][jj] + (float)xzv[1][jj] + bs[1][jj]);
      float O  = sigmoid_f(z[2][jj] + (float)xzv[2][jj] + bs[2][jj]);
      float Ct = b2bsqrt_f(z[3][jj] + (float)xzv[3][jj] + bs[3][jj]);
      float c2 = Fg * creg[jj] + I * Ct;
      creg[jj] = c2;
      hb[jj] = (bf16)(O * b2bsqrt_f(c2));
    }
    *(bf16x4*)(hnx + (size_t)gb * H_ + gh) = hb;

    // ---- hierarchical device-scope grid barrier (skip after last step) ----
    if (tt < TC_ - 1) {
      btarget += 16u;
      __syncthreads();                        // drains vmcnt(0): hnx stores in L2
      if (tid == 0) {
        __threadfence();                      // agent release: L2 writeback
        unsigned old = atomicAdd(&bar[(bid & 15) * 32], 1u);  // 16 groups, 128B apart
        if ((old & 15u) == 15u) atomicAdd(&bar[512], 1u);     // group complete -> root
        unsigned spins = 0;
        while (__hip_atomic_load(&bar[512], __ATOMIC_RELAXED, __HIP_MEMORY_SCOPE_AGENT)
               < btarget) {
          __builtin_amdgcn_s_sleep(2);
          if (++spins > (1u << 20)) break;    // bounded: fail loud, never hang
        }
        __threadfence();                      // agent acquire: invalidate caches
      }
      __syncthreads();
    }
  }

  // write back persistent c-state for the next chunk's launch
  *(f32x4*)(cst + (size_t)gb * H_ + gh) = creg;
}

// ------------- LN+FC as MFMA GEMM (unchanged) -------------
__global__ __launch_bounds__(256) void ln_fc_kernel(
    const bf16* __restrict__ hseq1, const bf16* __restrict__ Bt,
    const float* __restrict__ SA, float* __restrict__ out) {
  __shared__ bf16 sA[64 * 64];
  __shared__ bf16 sBt[16 * 1040];
  __shared__ float sLg[4][16 * 17];
  __shared__ float sSq[4][16];
  const int tid = threadIdx.x;
  const int lane = tid & 63;
  const int w = tid >> 6;
  const int l16 = lane & 15;
  const int quad = lane >> 4;
  const int m0 = blockIdx.x * 64;
  const int rL = lane >> 3;
  const int gch = (lane & 7) ^ rL;

  #pragma unroll
  for (int i = 0; i < 8; ++i) {
    int ch = tid + i * 256;
    int n = ch >> 7, k8 = ch & 127;
    *(bf16x8*)(sBt + n * 1040 + k8 * 8) = *(const bf16x8*)(Bt + n * 1024 + k8 * 8);
  }

  f32x4 acc = {};
  float sq = 0.f;

  for (int kk = 0; kk < 1024; kk += 64) {
    #pragma unroll
    for (int j = 0; j < 2; ++j) {
      int r0 = (w * 2 + j) * 8;
      int r = r0 + rL;
      glds16(hseq1 + (size_t)(m0 + r) * 1024 + kk + gch * 8, sA + r0 * 64);
    }
    __syncthreads();
    #pragma unroll
    for (int kh = 0; kh < 2; ++kh) {
      const int slot = (kh * 4 + quad) ^ (l16 & 7);
      bf16x8 aF = *(const bf16x8*)(sA + (w * 16 + l16) * 64 + slot * 8);
      bf16x8 bF = *(const bf16x8*)(sBt + l16 * 1040 + kk + kh * 32 + quad * 8);
      acc = MFMA16x16x32(aF, bF, acc);
      #pragma unroll
      for (int e = 0; e < 8; ++e) { float f = (float)aF[e]; sq += f * f; }
    }
    __syncthreads();
  }

  sq += __shfl_xor(sq, 16, 64);
  sq += __shfl_xor(sq, 32, 64);

  #pragma unroll
  for (int r = 0; r < 4; ++r)
    sLg[w][(quad * 4 + r) * 17 + l16] = acc[r];
  if (quad == 0) sSq[w][l16] = sq;
  __syncthreads();

  if (lane < 16) {
    int row = lane;
    float sum = sLg[w][row * 17 + 10];
    float ssq = sSq[w][row];
    float mu = sum * (1.0f / 1024.0f);
    float var = ssq * (1.0f / 1024.0f) - mu * mu;
    float rs = rsqrtf(var + 1e-5f);
    int rg = m0 + w * 16 + row;
    int t = rg >> 9, b = rg & 511;
    float* op = out + ((size_t)b * 100 + t) * 10;
    #pragma unroll
    for (int c = 0; c < 10; ++c)
      op[c] = rs * (sLg[w][row * 17 + c] - mu * SA[c]) + SA[16 + c];
  }
}

extern "C" void kernel_launch(void* const* d_in, const int* in_sizes, int n_in,
                              void* d_out, int out_size, void* d_ws, size_t ws_size,
                              hipStream_t stream) {
  (void)in_sizes; (void)n_in; (void)out_size; (void)ws_size;
  const float* x    = (const float*)d_in[0];
  const float* W    = (const float*)d_in[1];
  const float* U    = (const float*)d_in[2];
  const float* bias = (const float*)d_in[3];
  const float* lng  = (const float*)d_in[4];
  const float* lnb  = (const float*)d_in[5];
  const float* fcw  = (const float*)d_in[6];
  const float* fcb  = (const float*)d_in[7];
  float* out = (float*)d_out;

  char* ws = (char*)d_ws;
  size_t off = 0;
  bf16* Wt   = (bf16*)(ws + off); off += (size_t)4 * F_ * H_ * 2;
  bf16* Ut   = (bf16*)(ws + off); off += (size_t)4 * H_ * H_ * 2;
  bf16* XZc  = (bf16*)(ws + off); off += (size_t)TC_ * 4 * B_ * H_ * 2;
  bf16* hseq = (bf16*)(ws + off); off += (size_t)(T_ + 1) * B_ * H_ * 2;
  float* cst = (float*)(ws + off); off += (size_t)B_ * H_ * 4;
  bf16* xbf  = (bf16*)(ws + off); off += (size_t)B_ * TC_ * F_ * 2;
  bf16* Bt   = (bf16*)(ws + off); off += (size_t)16 * H_ * 2;
  float* SA  = (float*)(ws + off); off += 32 * 4;
  unsigned* bars = (unsigned*)(ws + off); off += 10 * 1024 * 4;  // 10 chunks x 1024 dwords

  zero_init<<<(B_ * H_ + 255) / 256, 256, 0, stream>>>(hseq, cst, bars, B_ * H_);
  tr_kernel<<<dim3(32, 32, 4), 256, 0, stream>>>(W, Wt);
  tr_kernel<<<dim3(32, 32, 4), 256, 0, stream>>>(U, Ut);
  prep_fc<<<16, 256, 0, stream>>>(lng, lnb, fcw, fcb, Bt, SA);

  for (int chunk = 0; chunk < T_ / TC_; ++chunk) {
    int t0 = chunk * TC_;
    convx<<<(B_ * TC_) / 4, 256, 0, stream>>>(x, xbf, t0);
    gemm_xz<<<dim3(32, (B_ * TC_) / 128), 256, 0, stream>>>(xbf, Wt, XZc);
    step_persist<<<256, 512, 0, stream>>>(t0, XZc, Ut, bias, hseq, cst,
                                          bars + chunk * 1024);
  }

  ln_fc_kernel<<<(B_ * T_) / 64, 256, 0, stream>>>(hseq + (size_t)B_ * H_, Bt, SA, out);
}

// Round 3
// 2060.657 us; speedup vs baseline: 1.7488x; 1.2922x over previous
//
#include <hip/hip_runtime.h>
#include <stdint.h>

typedef __bf16 bf16;
typedef __bf16 bf16x4 __attribute__((ext_vector_type(4)));
typedef __bf16 bf16x8 __attribute__((ext_vector_type(8)));
typedef float f32x4 __attribute__((ext_vector_type(4)));
typedef unsigned int u32x2 __attribute__((ext_vector_type(2)));

#define MFMA16x16x32(A, B, C) __builtin_amdgcn_mfma_f32_16x16x32_bf16((A), (B), (C), 0, 0, 0)

#define B_ 512
#define T_ 100
#define F_ 1024
#define H_ 1024
#define TC_ 10  // T-chunk

__device__ __forceinline__ float sigmoid_f(float x) { return 1.0f / (1.0f + __expf(-x)); }
__device__ __forceinline__ float b2bsqrt_f(float x) {
  float s = sqrtf(1.0f + fabsf(x)) - 1.0f;
  return x >= 0.0f ? s : -s;
}

// async global->LDS, 16B per lane; LDS dest = wave-uniform base + lane*16
__device__ __forceinline__ void glds16(const void* g, void* l) {
  __builtin_amdgcn_global_load_lds((const __attribute__((address_space(1))) void*)g,
                                   (__attribute__((address_space(3))) void*)l, 16, 0, 0);
}

// ---------------- zero-init h slot 0, c state, barrier counters ----------------
__global__ __launch_bounds__(256) void zero_init(bf16* __restrict__ h0,
                                                 float* __restrict__ c0,
                                                 unsigned* __restrict__ bars, int n) {
  int i = blockIdx.x * blockDim.x + threadIdx.x;
  if (i < n) { h0[i] = (bf16)0.0f; c0[i] = 0.0f; }
  if (i < 10 * 1024) bars[i] = 0u;   // 10 chunks x 1024 dwords of barrier state
}

// ---------- transpose per gate: fp32 (1024 x 1024) -> bf16 transposed ----------
__global__ __launch_bounds__(256) void tr_kernel(const float* __restrict__ src,
                                                 bf16* __restrict__ dst) {
  __shared__ float tile[32][33];
  int g = blockIdx.z;
  int c0 = blockIdx.x * 32;
  int r0 = blockIdx.y * 32;
  const float* s = src + (size_t)g * 1024 * 1024;
  bf16* d = dst + (size_t)g * 1024 * 1024;
  int tx = threadIdx.x & 31, ty = threadIdx.x >> 5;
  #pragma unroll
  for (int i = 0; i < 32; i += 8)
    tile[ty + i][tx] = s[(size_t)(r0 + ty + i) * 1024 + c0 + tx];
  __syncthreads();
  #pragma unroll
  for (int i = 0; i < 32; i += 8)
    d[(size_t)(c0 + ty + i) * 1024 + r0 + tx] = (bf16)tile[tx][ty + i];
}

// ---------- convert x chunk fp32 -> bf16 ----------
__global__ __launch_bounds__(256) void convx(const float* __restrict__ x,
                                             bf16* __restrict__ xbf, int t0) {
  int lr = blockIdx.x * 4 + (threadIdx.x >> 6);
  int lane = threadIdx.x & 63;
  unsigned b = (unsigned)lr / 10u;
  unsigned tt = (unsigned)lr - b * 10u;
  const float* src = x + (size_t)(b * 100u + (unsigned)t0 + tt) * 1024;
  bf16* dst = xbf + (size_t)lr * 1024;
  #pragma unroll
  for (int j = 0; j < 4; ++j) {
    f32x4 f = *(const f32x4*)(src + (j * 64 + lane) * 4);
    bf16x4 o;
    o[0] = (bf16)f[0]; o[1] = (bf16)f[1]; o[2] = (bf16)f[2]; o[3] = (bf16)f[3];
    *(bf16x4*)(dst + (j * 64 + lane) * 4) = o;
  }
}

// ---------- prep FC (unchanged) ----------
__global__ __launch_bounds__(256) void prep_fc(const float* __restrict__ lng,
                                               const float* __restrict__ lnb,
                                               const float* __restrict__ fcw,
                                               const float* __restrict__ fcb,
                                               bf16* __restrict__ Bt,
                                               float* __restrict__ SA) {
  __shared__ float red[2][256];
  int c = blockIdx.x;
  int tid = threadIdx.x;
  float pS = 0.f, pA = 0.f;
  #pragma unroll
  for (int j = 0; j < 4; ++j) {
    int h = j * 256 + tid;
    float v;
    if (c < 10) {
      float wv = fcw[h * 10 + c];
      v = lng[h] * wv;
      pS += v;
      pA += lnb[h] * wv;
    } else {
      v = (c == 10) ? 1.0f : 0.0f;
    }
    Bt[c * 1024 + h] = (bf16)v;
  }
  if (c < 10) {
    red[0][tid] = pS; red[1][tid] = pA;
    __syncthreads();
    for (int s = 128; s > 0; s >>= 1) {
      if (tid < s) { red[0][tid] += red[0][tid + s]; red[1][tid] += red[1][tid + s]; }
      __syncthreads();
    }
    if (tid == 0) { SA[c] = red[0][0]; SA[16 + c] = red[1][0] + fcb[c]; }
  }
}

// ---------------- xz chunk GEMM (m97-style, unchanged) ----------------
__global__ __launch_bounds__(256) void gemm_xz(const bf16* __restrict__ X,
                                               const bf16* __restrict__ Wt,
                                               bf16* __restrict__ XZc) {
  __shared__ bf16 sA[128 * 32];
  __shared__ bf16 sB[128 * 32];
  const int tid = threadIdx.x;
  const int lane = tid & 63;
  const int w = tid >> 6;
  const int l16 = lane & 15;
  const int quad = lane >> 4;
  const int m0 = blockIdx.y * 128;
  const int n0 = blockIdx.x * 128;
  const int wm = (w >> 1) * 64;
  const int wn = (w & 1) * 64;
  const int rA = lane >> 2;
  const int gch = (lane & 3) ^ (rA & 3);

  f32x4 acc[4][4] = {};

  for (int kk = 0; kk < 1024; kk += 32) {
    #pragma unroll
    for (int j = 0; j < 2; ++j) {
      int r0 = (w * 2 + j) * 16;
      int r = r0 + rA;
      glds16(X + (size_t)(m0 + r) * 1024 + kk + gch * 8, sA + r0 * 32);
      glds16(Wt + (size_t)(n0 + r) * 1024 + kk + gch * 8, sB + r0 * 32);
    }
    __syncthreads();
    bf16x8 aF[4], bF[4];
    const int slot = quad ^ (l16 & 3);
    #pragma unroll
    for (int mt = 0; mt < 4; ++mt)
      aF[mt] = *(const bf16x8*)(sA + (wm + mt * 16 + l16) * 32 + slot * 8);
    #pragma unroll
    for (int nt = 0; nt < 4; ++nt)
      bF[nt] = *(const bf16x8*)(sB + (wn + nt * 16 + l16) * 32 + slot * 8);
    #pragma unroll
    for (int mt = 0; mt < 4; ++mt)
      #pragma unroll
      for (int nt = 0; nt < 4; ++nt)
        acc[mt][nt] = MFMA16x16x32(aF[mt], bF[nt], acc[mt][nt]);
    __syncthreads();
  }

  #pragma unroll
  for (int mt = 0; mt < 4; ++mt) {
    #pragma unroll
    for (int r = 0; r < 4; ++r) {
      unsigned lr = (unsigned)(m0 + wm + mt * 16 + quad * 4 + r);
      unsigned b = lr / 10u;
      unsigned tt = lr - b * 10u;
      #pragma unroll
      for (int nt = 0; nt < 4; ++nt) {
        int n = n0 + wn + nt * 16 + l16;
        int g = n >> 10;
        int hh = n & 1023;
        XZc[((size_t)(tt * 4 + g) * B_ + b) * H_ + hh] = (bf16)acc[mt][nt][r];
      }
    }
  }
}

// ------------- persistent recurrence v3 -------------
// 256 blocks x 512 thr, launch_bounds(512,1): Ut B-frags truly VGPR-resident (128 VGPR).
// bm = bid&7 (64 b-rows), hn = bid>>3 (32 h-cols). Wave w: gate=w&3, K-half hf=w>>2.
// Per step: stage ALL 4 K-tiles (BK=256) up front via global_load_lds, counted
// vmcnt(12/8/4/0) + one s_barrier per tile. Z-scratch is UNION'd over the A-tiles
// (only live after all staging retired).
// Coherence: h stores are sc0 sc1 (write-through to mall = cross-XCD coherent point);
// release = vmcnt drain in __syncthreads; acquire = fence(acquire, agent) by tid0
// (invalidate only, no wbl2). No __threadfence anywhere.
__global__ __launch_bounds__(512, 1) void step_persist(
    int t0,
    const bf16* __restrict__ XZc,    // (TC,4,B,H) bf16
    const bf16* __restrict__ Ut,     // (4096,1024): row n=g*1024+h, col k
    const float* __restrict__ bias,  // (4,H)
    bf16* __restrict__ hseq,         // slots t0..t0+TC
    float* __restrict__ cst,         // (B,H) fp32
    unsigned* __restrict__ bar) {    // this chunk's barrier state (1024 dwords)
  __shared__ __align__(16) unsigned char smem[131072];  // 128 KB
  bf16* sA = (bf16*)smem;            // [4 tiles][64 rows][256 k] bf16
  float* sZf = (float*)smem;         // overlay: [8 waves][64*36] f32 (73728 B)

  const int tid = threadIdx.x;
  const int lane = tid & 63;
  const int w = tid >> 6;            // 0..7
  const int gate = w & 3;
  const int hf = w >> 2;             // K-half of each 256-tile
  const int l16 = lane & 15;
  const int quad = lane >> 4;
  const int bid = blockIdx.x;
  const int bm0 = (bid & 7) * 64;
  const int hn0 = (bid >> 3) * 32;

  // ---- persistent B fragments (VGPR): bfr[nt][t*4+kh] over k = t*256+hf*128+kh*32+quad*8
  bf16x8 bfr[2][16];
  #pragma unroll
  for (int nt = 0; nt < 2; ++nt) {
    const bf16* up = Ut + (size_t)((gate << 10) + hn0 + nt * 16 + l16) * 1024 + hf * 128 + quad * 8;
    #pragma unroll
    for (int t = 0; t < 4; ++t)
      #pragma unroll
      for (int kh = 0; kh < 4; ++kh)
        bfr[nt][t * 4 + kh] = *(const bf16x8*)(up + t * 256 + kh * 32);
  }

  // ---- gate-phase mapping: row rr (0..63) x 4 h-cols; persistent c-state, bias hoisted
  const int rr = tid >> 3;
  const int cc = (tid & 7) * 4;
  const int gb = bm0 + rr;
  const int gh = hn0 + cc;
  f32x4 creg = *(const f32x4*)(cst + (size_t)gb * H_ + gh);
  f32x4 bs[4];
  #pragma unroll
  for (int g = 0; g < 4; ++g) bs[g] = *(const f32x4*)(bias + g * H_ + gh);

  // staging geometry: wave w, issue i stages rows w*8+i*2+{0,1} of a tile.
  // lane l -> row +(l>>5), 16B-chunk l&31. Swizzle: LDS[r][x] holds global chunk x^(r&15).
  const int srow = w * 8 + (lane >> 5);  // row this lane covers (before +i*2)
  const int lch = lane & 31;

  // xz prefetch for step 0
  bf16x4 xzv[4];
  #pragma unroll
  for (int g = 0; g < 4; ++g)
    xzv[g] = *(const bf16x4*)(XZc + ((size_t)(0 * 4 + g) * B_ + gb) * H_ + gh);

  unsigned btarget = 0;

  for (int tt = 0; tt < TC_; ++tt) {
    const bf16* hp = hseq + (size_t)(t0 + tt) * B_ * H_;
    bf16* hnx = hseq + (size_t)(t0 + tt + 1) * B_ * H_;

    // ---- prologue: stage all 4 K-tiles (16 glds16 per thread)
    #pragma unroll
    for (int t = 0; t < 4; ++t)
      #pragma unroll
      for (int i = 0; i < 4; ++i) {
        const int r = bm0 + srow + i * 2;
        glds16(hp + (size_t)r * 1024 + (size_t)(t * 32 + (lch ^ (r & 15))) * 8,
               smem + t * 32768 + (size_t)(w * 8 + i * 2) * 512);
      }

    f32x4 acc[4][2] = {};

    #pragma unroll
    for (int t = 0; t < 4; ++t) {
      if (t == 0)      asm volatile("s_waitcnt vmcnt(12)" ::: "memory");
      else if (t == 1) asm volatile("s_waitcnt vmcnt(8)" ::: "memory");
      else if (t == 2) asm volatile("s_waitcnt vmcnt(4)" ::: "memory");
      else             asm volatile("s_waitcnt vmcnt(0)" ::: "memory");
      __builtin_amdgcn_sched_barrier(0);
      __builtin_amdgcn_s_barrier();           // tile t staged by every wave
      __builtin_amdgcn_sched_barrier(0);
      #pragma unroll
      for (int kh = 0; kh < 4; ++kh) {
        const int S = hf * 16 + kh * 4 + quad;       // logical 16B chunk 0..31
        const int slot = S ^ l16;                    // XOR-swizzled read slot
        bf16x8 aF[4];
        #pragma unroll
        for (int mt = 0; mt < 4; ++mt)
          aF[mt] = *(const bf16x8*)(sA + (size_t)t * 16384 + (mt * 16 + l16) * 256 + slot * 8);
        #pragma unroll
        for (int mt = 0; mt < 4; ++mt) {
          acc[mt][0] = MFMA16x16x32(aF[mt], bfr[0][t * 4 + kh], acc[mt][0]);
          acc[mt][1] = MFMA16x16x32(aF[mt], bfr[1][t * 4 + kh], acc[mt][1]);
        }
      }
      __builtin_amdgcn_sched_barrier(0);
    }

    // ---- Z dump into overlay (all staging retired at vmcnt(0); tile3 region not aliased)
    #pragma unroll
    for (int mt = 0; mt < 4; ++mt)
      #pragma unroll
      for (int nt = 0; nt < 2; ++nt)
        #pragma unroll
        for (int r = 0; r < 4; ++r)
          sZf[w * 2304 + (mt * 16 + quad * 4 + r) * 36 + nt * 16 + l16] = acc[mt][nt][r];
    __syncthreads();

    // ---- gates: 4 h per thread; z = K-half0 + K-half1
    f32x4 z[4];
    #pragma unroll
    for (int g = 0; g < 4; ++g) {
      f32x4 za = *(const f32x4*)(sZf + g * 2304 + rr * 36 + cc);
      f32x4 zb = *(const f32x4*)(sZf + (g + 4) * 2304 + rr * 36 + cc);
      z[g] = za + zb;
    }
    bf16x4 hb;
    #pragma unroll
    for (int jj = 0; jj < 4; ++jj) {
      float I  = sigmoid_f(z[0][jj] + (float)xzv[0][jj] + bs[0][jj]);
      float Fg = sigmoid_f(z[1][jj] + (float)xzv[1][jj] + bs[1][jj]);
      float O  = sigmoid_f(z[2][jj] + (float)xzv[2][jj] + bs[2][jj]);
      float Ct = b2bsqrt_f(z[3][jj] + (float)xzv[3][jj] + bs[3][jj]);
      float c2 = Fg * creg[jj] + I * Ct;
      creg[jj] = c2;
      hb[jj] = (bf16)(O * b2bsqrt_f(c2));
    }
    // h store: sc0 sc1 write-through -> visible at mall (cross-XCD coherent point)
    {
      u32x2 hbu = __builtin_bit_cast(u32x2, hb);
      bf16* ha = hnx + (size_t)gb * H_ + gh;
      asm volatile("global_store_dwordx2 %0, %1, off sc0 sc1" :: "v"(ha), "v"(hbu) : "memory");
    }

    if (tt < TC_ - 1) {
      // prefetch next step's xz while we wait at the barrier
      #pragma unroll
      for (int g = 0; g < 4; ++g)
        xzv[g] = *(const bf16x4*)(XZc + ((size_t)((tt + 1) * 4 + g) * B_ + gb) * H_ + gh);

      btarget += 16u;
      __syncthreads();                        // emits s_waitcnt vmcnt(0): h stores acked at mall
      if (tid == 0) {
        unsigned old = atomicAdd(&bar[(bid & 15) * 32], 1u);   // 16 groups x 16 blocks
        if ((old & 15u) == 15u) atomicAdd(&bar[512], 1u);      // group done -> root
        unsigned spins = 0;
        while (__hip_atomic_load(&bar[512], __ATOMIC_RELAXED, __HIP_MEMORY_SCOPE_AGENT)
               < btarget) {
          __builtin_amdgcn_s_sleep(2);
          if (++spins > (1u << 20)) break;    // bounded: fail loud, never hang
        }
        __builtin_amdgcn_fence(__ATOMIC_ACQUIRE, "agent");     // inv L1/L2, no writeback
      }
      __syncthreads();
    }
  }

  // write back persistent c-state for the next chunk's launch
  *(f32x4*)(cst + (size_t)gb * H_ + gh) = creg;
}

// ------------- LN+FC as MFMA GEMM (unchanged) -------------
__global__ __launch_bounds__(256) void ln_fc_kernel(
    const bf16* __restrict__ hseq1, const bf16* __restrict__ Bt,
    const float* __restrict__ SA, float* __restrict__ out) {
  __shared__ bf16 sA[64 * 64];
  __shared__ bf16 sBt[16 * 1040];
  __shared__ float sLg[4][16 * 17];
  __shared__ float sSq[4][16];
  const int tid = threadIdx.x;
  const int lane = tid & 63;
  const int w = tid >> 6;
  const int l16 = lane & 15;
  const int quad = lane >> 4;
  const int m0 = blockIdx.x * 64;
  const int rL = lane >> 3;
  const int gch = (lane & 7) ^ rL;

  #pragma unroll
  for (int i = 0; i < 8; ++i) {
    int ch = tid + i * 256;
    int n = ch >> 7, k8 = ch & 127;
    *(bf16x8*)(sBt + n * 1040 + k8 * 8) = *(const bf16x8*)(Bt + n * 1024 + k8 * 8);
  }

  f32x4 acc = {};
  float sq = 0.f;

  for (int kk = 0; kk < 1024; kk += 64) {
    #pragma unroll
    for (int j = 0; j < 2; ++j) {
      int r0 = (w * 2 + j) * 8;
      int r = r0 + rL;
      glds16(hseq1 + (size_t)(m0 + r) * 1024 + kk + gch * 8, sA + r0 * 64);
    }
    __syncthreads();
    #pragma unroll
    for (int kh = 0; kh < 2; ++kh) {
      const int slot = (kh * 4 + quad) ^ (l16 & 7);
      bf16x8 aF = *(const bf16x8*)(sA + (w * 16 + l16) * 64 + slot * 8);
      bf16x8 bF = *(const bf16x8*)(sBt + l16 * 1040 + kk + kh * 32 + quad * 8);
      acc = MFMA16x16x32(aF, bF, acc);
      #pragma unroll
      for (int e = 0; e < 8; ++e) { float f = (float)aF[e]; sq += f * f; }
    }
    __syncthreads();
  }

  sq += __shfl_xor(sq, 16, 64);
  sq += __shfl_xor(sq, 32, 64);

  #pragma unroll
  for (int r = 0; r < 4; ++r)
    sLg[w][(quad * 4 + r) * 17 + l16] = acc[r];
  if (quad == 0) sSq[w][l16] = sq;
  __syncthreads();

  if (lane < 16) {
    int row = lane;
    float sum = sLg[w][row * 17 + 10];
    float ssq = sSq[w][row];
    float mu = sum * (1.0f / 1024.0f);
    float var = ssq * (1.0f / 1024.0f) - mu * mu;
    float rs = rsqrtf(var + 1e-5f);
    int rg = m0 + w * 16 + row;
    int t = rg >> 9, b = rg & 511;
    float* op = out + ((size_t)b * 100 + t) * 10;
    #pragma unroll
    for (int c = 0; c < 10; ++c)
      op[c] = rs * (sLg[w][row * 17 + c] - mu * SA[c]) + SA[16 + c];
  }
}

extern "C" void kernel_launch(void* const* d_in, const int* in_sizes, int n_in,
                              void* d_out, int out_size, void* d_ws, size_t ws_size,
                              hipStream_t stream) {
  (void)in_sizes; (void)n_in; (void)out_size; (void)ws_size;
  const float* x    = (const float*)d_in[0];
  const float* W    = (const float*)d_in[1];
  const float* U    = (const float*)d_in[2];
  const float* bias = (const float*)d_in[3];
  const float* lng  = (const float*)d_in[4];
  const float* lnb  = (const float*)d_in[5];
  const float* fcw  = (const float*)d_in[6];
  const float* fcb  = (const float*)d_in[7];
  float* out = (float*)d_out;

  char* ws = (char*)d_ws;
  size_t off = 0;
  bf16* Wt   = (bf16*)(ws + off); off += (size_t)4 * F_ * H_ * 2;
  bf16* Ut   = (bf16*)(ws + off); off += (size_t)4 * H_ * H_ * 2;
  bf16* XZc  = (bf16*)(ws + off); off += (size_t)TC_ * 4 * B_ * H_ * 2;
  bf16* hseq = (bf16*)(ws + off); off += (size_t)(T_ + 1) * B_ * H_ * 2;
  float* cst = (float*)(ws + off); off += (size_t)B_ * H_ * 4;
  bf16* xbf  = (bf16*)(ws + off); off += (size_t)B_ * TC_ * F_ * 2;
  bf16* Bt   = (bf16*)(ws + off); off += (size_t)16 * H_ * 2;
  float* SA  = (float*)(ws + off); off += 32 * 4;
  unsigned* bars = (unsigned*)(ws + off); off += 10 * 1024 * 4;  // 10 chunks x 1024 dwords

  zero_init<<<(B_ * H_ + 255) / 256, 256, 0, stream>>>(hseq, cst, bars, B_ * H_);
  tr_kernel<<<dim3(32, 32, 4), 256, 0, stream>>>(W, Wt);
  tr_kernel<<<dim3(32, 32, 4), 256, 0, stream>>>(U, Ut);
  prep_fc<<<16, 256, 0, stream>>>(lng, lnb, fcw, fcb, Bt, SA);

  for (int chunk = 0; chunk < T_ / TC_; ++chunk) {
    int t0 = chunk * TC_;
    convx<<<(B_ * TC_) / 4, 256, 0, stream>>>(x, xbf, t0);
    gemm_xz<<<dim3(32, (B_ * TC_) / 128), 256, 0, stream>>>(xbf, Wt, XZc);
    step_persist<<<256, 512, 0, stream>>>(t0, XZc, Ut, bias, hseq, cst,
                                          bars + chunk * 1024);
  }

  ln_fc_kernel<<<(B_ * T_) / 64, 256, 0, stream>>>(hseq + (size_t)B_ * H_, Bt, SA, out);
}

// Round 4
// 1803.407 us; speedup vs baseline: 1.9983x; 1.1426x over previous
//
#include <hip/hip_runtime.h>
#include <stdint.h>

typedef __bf16 bf16;
typedef __bf16 bf16x4 __attribute__((ext_vector_type(4)));
typedef __bf16 bf16x8 __attribute__((ext_vector_type(8)));
typedef float f32x4 __attribute__((ext_vector_type(4)));
typedef unsigned int u32x2 __attribute__((ext_vector_type(2)));

#define MFMA16x16x32(A, B, C) __builtin_amdgcn_mfma_f32_16x16x32_bf16((A), (B), (C), 0, 0, 0)

#define B_ 512
#define T_ 100
#define F_ 1024
#define H_ 1024
#define TC_ 10  // T-chunk

__device__ __forceinline__ float sigmoid_f(float x) { return 1.0f / (1.0f + __expf(-x)); }
__device__ __forceinline__ float b2bsqrt_f(float x) {
  float s = sqrtf(1.0f + fabsf(x)) - 1.0f;
  return x >= 0.0f ? s : -s;
}

// async global->LDS, 16B per lane; LDS dest = wave-uniform base + lane*16
__device__ __forceinline__ void glds16(const void* g, void* l) {
  __builtin_amdgcn_global_load_lds((const __attribute__((address_space(1))) void*)g,
                                   (__attribute__((address_space(3))) void*)l, 16, 0, 0);
}

// ---------------- zero-init h slot 0, c state, barrier counters ----------------
__global__ __launch_bounds__(256) void zero_init(bf16* __restrict__ h0,
                                                 float* __restrict__ c0,
                                                 unsigned* __restrict__ bars, int n) {
  int i = blockIdx.x * blockDim.x + threadIdx.x;
  if (i < n) { h0[i] = (bf16)0.0f; c0[i] = 0.0f; }
  if (i < 10 * 1024) bars[i] = 0u;   // 10 chunks x 1024 dwords of barrier state
}

// ---------- transpose per gate: fp32 (1024 x 1024) -> bf16 transposed ----------
__global__ __launch_bounds__(256) void tr_kernel(const float* __restrict__ src,
                                                 bf16* __restrict__ dst) {
  __shared__ float tile[32][33];
  int g = blockIdx.z;
  int c0 = blockIdx.x * 32;
  int r0 = blockIdx.y * 32;
  const float* s = src + (size_t)g * 1024 * 1024;
  bf16* d = dst + (size_t)g * 1024 * 1024;
  int tx = threadIdx.x & 31, ty = threadIdx.x >> 5;
  #pragma unroll
  for (int i = 0; i < 32; i += 8)
    tile[ty + i][tx] = s[(size_t)(r0 + ty + i) * 1024 + c0 + tx];
  __syncthreads();
  #pragma unroll
  for (int i = 0; i < 32; i += 8)
    d[(size_t)(c0 + ty + i) * 1024 + r0 + tx] = (bf16)tile[tx][ty + i];
}

// ---------- convert x chunk fp32 -> bf16 ----------
__global__ __launch_bounds__(256) void convx(const float* __restrict__ x,
                                             bf16* __restrict__ xbf, int t0) {
  int lr = blockIdx.x * 4 + (threadIdx.x >> 6);
  int lane = threadIdx.x & 63;
  unsigned b = (unsigned)lr / 10u;
  unsigned tt = (unsigned)lr - b * 10u;
  const float* src = x + (size_t)(b * 100u + (unsigned)t0 + tt) * 1024;
  bf16* dst = xbf + (size_t)lr * 1024;
  #pragma unroll
  for (int j = 0; j < 4; ++j) {
    f32x4 f = *(const f32x4*)(src + (j * 64 + lane) * 4);
    bf16x4 o;
    o[0] = (bf16)f[0]; o[1] = (bf16)f[1]; o[2] = (bf16)f[2]; o[3] = (bf16)f[3];
    *(bf16x4*)(dst + (j * 64 + lane) * 4) = o;
  }
}

// ---------- prep FC (unchanged) ----------
__global__ __launch_bounds__(256) void prep_fc(const float* __restrict__ lng,
                                               const float* __restrict__ lnb,
                                               const float* __restrict__ fcw,
                                               const float* __restrict__ fcb,
                                               bf16* __restrict__ Bt,
                                               float* __restrict__ SA) {
  __shared__ float red[2][256];
  int c = blockIdx.x;
  int tid = threadIdx.x;
  float pS = 0.f, pA = 0.f;
  #pragma unroll
  for (int j = 0; j < 4; ++j) {
    int h = j * 256 + tid;
    float v;
    if (c < 10) {
      float wv = fcw[h * 10 + c];
      v = lng[h] * wv;
      pS += v;
      pA += lnb[h] * wv;
    } else {
      v = (c == 10) ? 1.0f : 0.0f;
    }
    Bt[c * 1024 + h] = (bf16)v;
  }
  if (c < 10) {
    red[0][tid] = pS; red[1][tid] = pA;
    __syncthreads();
    for (int s = 128; s > 0; s >>= 1) {
      if (tid < s) { red[0][tid] += red[0][tid + s]; red[1][tid] += red[1][tid + s]; }
      __syncthreads();
    }
    if (tid == 0) { SA[c] = red[0][0]; SA[16 + c] = red[1][0] + fcb[c]; }
  }
}

// ---------------- xz chunk GEMM (m97-style, unchanged) ----------------
__global__ __launch_bounds__(256) void gemm_xz(const bf16* __restrict__ X,
                                               const bf16* __restrict__ Wt,
                                               bf16* __restrict__ XZc) {
  __shared__ bf16 sA[128 * 32];
  __shared__ bf16 sB[128 * 32];
  const int tid = threadIdx.x;
  const int lane = tid & 63;
  const int w = tid >> 6;
  const int l16 = lane & 15;
  const int quad = lane >> 4;
  const int m0 = blockIdx.y * 128;
  const int n0 = blockIdx.x * 128;
  const int wm = (w >> 1) * 64;
  const int wn = (w & 1) * 64;
  const int rA = lane >> 2;
  const int gch = (lane & 3) ^ (rA & 3);

  f32x4 acc[4][4] = {};

  for (int kk = 0; kk < 1024; kk += 32) {
    #pragma unroll
    for (int j = 0; j < 2; ++j) {
      int r0 = (w * 2 + j) * 16;
      int r = r0 + rA;
      glds16(X + (size_t)(m0 + r) * 1024 + kk + gch * 8, sA + r0 * 32);
      glds16(Wt + (size_t)(n0 + r) * 1024 + kk + gch * 8, sB + r0 * 32);
    }
    __syncthreads();
    bf16x8 aF[4], bF[4];
    const int slot = quad ^ (l16 & 3);
    #pragma unroll
    for (int mt = 0; mt < 4; ++mt)
      aF[mt] = *(const bf16x8*)(sA + (wm + mt * 16 + l16) * 32 + slot * 8);
    #pragma unroll
    for (int nt = 0; nt < 4; ++nt)
      bF[nt] = *(const bf16x8*)(sB + (wn + nt * 16 + l16) * 32 + slot * 8);
    #pragma unroll
    for (int mt = 0; mt < 4; ++mt)
      #pragma unroll
      for (int nt = 0; nt < 4; ++nt)
        acc[mt][nt] = MFMA16x16x32(aF[mt], bF[nt], acc[mt][nt]);
    __syncthreads();
  }

  #pragma unroll
  for (int mt = 0; mt < 4; ++mt) {
    #pragma unroll
    for (int r = 0; r < 4; ++r) {
      unsigned lr = (unsigned)(m0 + wm + mt * 16 + quad * 4 + r);
      unsigned b = lr / 10u;
      unsigned tt = lr - b * 10u;
      #pragma unroll
      for (int nt = 0; nt < 4; ++nt) {
        int n = n0 + wn + nt * 16 + l16;
        int g = n >> 10;
        int hh = n & 1023;
        XZc[((size_t)(tt * 4 + g) * B_ + b) * H_ + hh] = (bf16)acc[mt][nt][r];
      }
    }
  }
}

// ------------- persistent recurrence v4: group-local sync -------------
// 256 blocks x 512 thr, launch_bounds(512,1). bm = bid&7 (64 b-rows), hn = bid>>3 (32 h-cols).
// DEPENDENCY CLOSURE: block (bm,hn) consumes h_prev[bm rows, ALL cols], produced by exactly
// the 32 blocks sharing bm. So the grid is 8 INDEPENDENT groups of 32 blocks (group = bid&7);
// sync is one 32-arrival counter per group — no global barrier, groups drift freely.
// Round-robin dispatch puts group g on XCD g (perf-only locality; correctness from
// agent-scope atomics + sc0sc1 write-through h stores + acquire fence, placement-independent).
// Wave w: gate=w&3, K-half hf=w>>2. Ut B-frags VGPR-resident; c-state in regs.
// Per step: stage all 4 K-tiles (BK=256) via global_load_lds, counted vmcnt(12/8/4/0),
// one s_barrier per tile; Z-scratch union'd over the A-tiles.
__global__ __launch_bounds__(512, 1) void step_persist(
    int t0,
    const bf16* __restrict__ XZc,    // (TC,4,B,H) bf16
    const bf16* __restrict__ Ut,     // (4096,1024): row n=g*1024+h, col k
    const float* __restrict__ bias,  // (4,H)
    bf16* __restrict__ hseq,         // slots t0..t0+TC
    float* __restrict__ cst,         // (B,H) fp32
    unsigned* __restrict__ bar) {    // this chunk's barrier state (1024 dwords)
  __shared__ __align__(16) unsigned char smem[131072];  // 128 KB
  bf16* sA = (bf16*)smem;            // [4 tiles][64 rows][256 k] bf16
  float* sZf = (float*)smem;         // overlay: [8 waves][64*36] f32 (73728 B)

  const int tid = threadIdx.x;
  const int lane = tid & 63;
  const int w = tid >> 6;            // 0..7
  const int gate = w & 3;
  const int hf = w >> 2;             // K-half of each 256-tile
  const int l16 = lane & 15;
  const int quad = lane >> 4;
  const int bid = blockIdx.x;
  const int bm0 = (bid & 7) * 64;
  const int hn0 = (bid >> 3) * 32;
  unsigned* const grp = &bar[(bid & 7) * 64];  // group counter, 256B apart

  // ---- persistent B fragments (VGPR): bfr[nt][t*4+kh] over k = t*256+hf*128+kh*32+quad*8
  bf16x8 bfr[2][16];
  #pragma unroll
  for (int nt = 0; nt < 2; ++nt) {
    const bf16* up = Ut + (size_t)((gate << 10) + hn0 + nt * 16 + l16) * 1024 + hf * 128 + quad * 8;
    #pragma unroll
    for (int t = 0; t < 4; ++t)
      #pragma unroll
      for (int kh = 0; kh < 4; ++kh)
        bfr[nt][t * 4 + kh] = *(const bf16x8*)(up + t * 256 + kh * 32);
  }

  // ---- gate-phase mapping: row rr (0..63) x 4 h-cols; persistent c-state, bias hoisted
  const int rr = tid >> 3;
  const int cc = (tid & 7) * 4;
  const int gb = bm0 + rr;
  const int gh = hn0 + cc;
  f32x4 creg = *(const f32x4*)(cst + (size_t)gb * H_ + gh);
  f32x4 bs[4];
  #pragma unroll
  for (int g = 0; g < 4; ++g) bs[g] = *(const f32x4*)(bias + g * H_ + gh);

  // staging geometry: wave w, issue i stages rows w*8+i*2+{0,1} of a tile.
  // lane l -> row +(l>>5), 16B-chunk l&31. Swizzle: LDS[r][x] holds global chunk x^(r&15).
  const int srow = w * 8 + (lane >> 5);  // row this lane covers (before +i*2)
  const int lch = lane & 31;

  // xz prefetch for step 0
  bf16x4 xzv[4];
  #pragma unroll
  for (int g = 0; g < 4; ++g)
    xzv[g] = *(const bf16x4*)(XZc + ((size_t)(0 * 4 + g) * B_ + gb) * H_ + gh);

  unsigned btarget = 0;

  for (int tt = 0; tt < TC_; ++tt) {
    const bf16* hp = hseq + (size_t)(t0 + tt) * B_ * H_;
    bf16* hnx = hseq + (size_t)(t0 + tt + 1) * B_ * H_;

    // ---- prologue: stage all 4 K-tiles (16 glds16 per thread)
    #pragma unroll
    for (int t = 0; t < 4; ++t)
      #pragma unroll
      for (int i = 0; i < 4; ++i) {
        const int r = bm0 + srow + i * 2;
        glds16(hp + (size_t)r * 1024 + (size_t)(t * 32 + (lch ^ (r & 15))) * 8,
               smem + t * 32768 + (size_t)(w * 8 + i * 2) * 512);
      }

    f32x4 acc[4][2] = {};

    #pragma unroll
    for (int t = 0; t < 4; ++t) {
      if (t == 0)      asm volatile("s_waitcnt vmcnt(12)" ::: "memory");
      else if (t == 1) asm volatile("s_waitcnt vmcnt(8)" ::: "memory");
      else if (t == 2) asm volatile("s_waitcnt vmcnt(4)" ::: "memory");
      else             asm volatile("s_waitcnt vmcnt(0)" ::: "memory");
      __builtin_amdgcn_sched_barrier(0);
      __builtin_amdgcn_s_barrier();           // tile t staged by every wave
      __builtin_amdgcn_sched_barrier(0);
      #pragma unroll
      for (int kh = 0; kh < 4; ++kh) {
        const int S = hf * 16 + kh * 4 + quad;       // logical 16B chunk 0..31
        const int slot = S ^ l16;                    // XOR-swizzled read slot
        bf16x8 aF[4];
        #pragma unroll
        for (int mt = 0; mt < 4; ++mt)
          aF[mt] = *(const bf16x8*)(sA + (size_t)t * 16384 + (mt * 16 + l16) * 256 + slot * 8);
        #pragma unroll
        for (int mt = 0; mt < 4; ++mt) {
          acc[mt][0] = MFMA16x16x32(aF[mt], bfr[0][t * 4 + kh], acc[mt][0]);
          acc[mt][1] = MFMA16x16x32(aF[mt], bfr[1][t * 4 + kh], acc[mt][1]);
        }
      }
      __builtin_amdgcn_sched_barrier(0);
    }

    // ---- Z dump into overlay (all staging retired at vmcnt(0))
    #pragma unroll
    for (int mt = 0; mt < 4; ++mt)
      #pragma unroll
      for (int nt = 0; nt < 2; ++nt)
        #pragma unroll
        for (int r = 0; r < 4; ++r)
          sZf[w * 2304 + (mt * 16 + quad * 4 + r) * 36 + nt * 16 + l16] = acc[mt][nt][r];
    __syncthreads();

    // ---- gates: 4 h per thread; z = K-half0 + K-half1
    f32x4 z[4];
    #pragma unroll
    for (int g = 0; g < 4; ++g) {
      f32x4 za = *(const f32x4*)(sZf + g * 2304 + rr * 36 + cc);
      f32x4 zb = *(const f32x4*)(sZf + (g + 4) * 2304 + rr * 36 + cc);
      z[g] = za + zb;
    }
    bf16x4 hb;
    #pragma unroll
    for (int jj = 0; jj < 4; ++jj) {
      float I  = sigmoid_f(z[0][jj] + (float)xzv[0][jj] + bs[0][jj]);
      float Fg = sigmoid_f(z[1][jj] + (float)xzv[1][jj] + bs[1][jj]);
      float O  = sigmoid_f(z[2][jj] + (float)xzv[2][jj] + bs[2][jj]);
      float Ct = b2bsqrt_f(z[3][jj] + (float)xzv[3][jj] + bs[3][jj]);
      float c2 = Fg * creg[jj] + I * Ct;
      creg[jj] = c2;
      hb[jj] = (bf16)(O * b2bsqrt_f(c2));
    }
    // h store: sc0 sc1 write-through -> visible at mall (cross-XCD coherent point)
    {
      u32x2 hbu = __builtin_bit_cast(u32x2, hb);
      bf16* ha = hnx + (size_t)gb * H_ + gh;
      asm volatile("global_store_dwordx2 %0, %1, off sc0 sc1" :: "v"(ha), "v"(hbu) : "memory");
    }

    if (tt < TC_ - 1) {
      // prefetch next step's xz while we wait at the barrier
      #pragma unroll
      for (int g = 0; g < 4; ++g)
        xzv[g] = *(const bf16x4*)(XZc + ((size_t)((tt + 1) * 4 + g) * B_ + gb) * H_ + gh);

      btarget += 32u;
      __syncthreads();                        // emits s_waitcnt vmcnt(0): h stores acked at mall
      if (tid == 0) {
        atomicAdd(grp, 1u);                   // fire-and-forget arrival
        unsigned spins = 0;
        while (__hip_atomic_load(grp, __ATOMIC_RELAXED, __HIP_MEMORY_SCOPE_AGENT)
               < btarget) {
          __builtin_amdgcn_s_sleep(1);
          if (++spins > (1u << 22)) break;    // bounded: fail loud, never hang
        }
        __builtin_amdgcn_fence(__ATOMIC_ACQUIRE, "agent");  // inv caches, no writeback
      }
      __syncthreads();
    }
  }

  // write back persistent c-state for the next chunk's launch
  *(f32x4*)(cst + (size_t)gb * H_ + gh) = creg;
}

// ------------- LN+FC as MFMA GEMM (unchanged) -------------
__global__ __launch_bounds__(256) void ln_fc_kernel(
    const bf16* __restrict__ hseq1, const bf16* __restrict__ Bt,
    const float* __restrict__ SA, float* __restrict__ out) {
  __shared__ bf16 sA[64 * 64];
  __shared__ bf16 sBt[16 * 1040];
  __shared__ float sLg[4][16 * 17];
  __shared__ float sSq[4][16];
  const int tid = threadIdx.x;
  const int lane = tid & 63;
  const int w = tid >> 6;
  const int l16 = lane & 15;
  const int quad = lane >> 4;
  const int m0 = blockIdx.x * 64;
  const int rL = lane >> 3;
  const int gch = (lane & 7) ^ rL;

  #pragma unroll
  for (int i = 0; i < 8; ++i) {
    int ch = tid + i * 256;
    int n = ch >> 7, k8 = ch & 127;
    *(bf16x8*)(sBt + n * 1040 + k8 * 8) = *(const bf16x8*)(Bt + n * 1024 + k8 * 8);
  }

  f32x4 acc = {};
  float sq = 0.f;

  for (int kk = 0; kk < 1024; kk += 64) {
    #pragma unroll
    for (int j = 0; j < 2; ++j) {
      int r0 = (w * 2 + j) * 8;
      int r = r0 + rL;
      glds16(hseq1 + (size_t)(m0 + r) * 1024 + kk + gch * 8, sA + r0 * 64);
    }
    __syncthreads();
    #pragma unroll
    for (int kh = 0; kh < 2; ++kh) {
      const int slot = (kh * 4 + quad) ^ (l16 & 7);
      bf16x8 aF = *(const bf16x8*)(sA + (w * 16 + l16) * 64 + slot * 8);
      bf16x8 bF = *(const bf16x8*)(sBt + l16 * 1040 + kk + kh * 32 + quad * 8);
      acc = MFMA16x16x32(aF, bF, acc);
      #pragma unroll
      for (int e = 0; e < 8; ++e) { float f = (float)aF[e]; sq += f * f; }
    }
    __syncthreads();
  }

  sq += __shfl_xor(sq, 16, 64);
  sq += __shfl_xor(sq, 32, 64);

  #pragma unroll
  for (int r = 0; r < 4; ++r)
    sLg[w][(quad * 4 + r) * 17 + l16] = acc[r];
  if (quad == 0) sSq[w][l16] = sq;
  __syncthreads();

  if (lane < 16) {
    int row = lane;
    float sum = sLg[w][row * 17 + 10];
    float ssq = sSq[w][row];
    float mu = sum * (1.0f / 1024.0f);
    float var = ssq * (1.0f / 1024.0f) - mu * mu;
    float rs = rsqrtf(var + 1e-5f);
    int rg = m0 + w * 16 + row;
    int t = rg >> 9, b = rg & 511;
    float* op = out + ((size_t)b * 100 + t) * 10;
    #pragma unroll
    for (int c = 0; c < 10; ++c)
      op[c] = rs * (sLg[w][row * 17 + c] - mu * SA[c]) + SA[16 + c];
  }
}

extern "C" void kernel_launch(void* const* d_in, const int* in_sizes, int n_in,
                              void* d_out, int out_size, void* d_ws, size_t ws_size,
                              hipStream_t stream) {
  (void)in_sizes; (void)n_in; (void)out_size; (void)ws_size;
  const float* x    = (const float*)d_in[0];
  const float* W    = (const float*)d_in[1];
  const float* U    = (const float*)d_in[2];
  const float* bias = (const float*)d_in[3];
  const float* lng  = (const float*)d_in[4];
  const float* lnb  = (const float*)d_in[5];
  const float* fcw  = (const float*)d_in[6];
  const float* fcb  = (const float*)d_in[7];
  float* out = (float*)d_out;

  char* ws = (char*)d_ws;
  size_t off = 0;
  bf16* Wt   = (bf16*)(ws + off); off += (size_t)4 * F_ * H_ * 2;
  bf16* Ut   = (bf16*)(ws + off); off += (size_t)4 * H_ * H_ * 2;
  bf16* XZc  = (bf16*)(ws + off); off += (size_t)TC_ * 4 * B_ * H_ * 2;
  bf16* hseq = (bf16*)(ws + off); off += (size_t)(T_ + 1) * B_ * H_ * 2;
  float* cst = (float*)(ws + off); off += (size_t)B_ * H_ * 4;
  bf16* xbf  = (bf16*)(ws + off); off += (size_t)B_ * TC_ * F_ * 2;
  bf16* Bt   = (bf16*)(ws + off); off += (size_t)16 * H_ * 2;
  float* SA  = (float*)(ws + off); off += 32 * 4;
  unsigned* bars = (unsigned*)(ws + off); off += 10 * 1024 * 4;  // 10 chunks x 1024 dwords

  zero_init<<<(B_ * H_ + 255) / 256, 256, 0, stream>>>(hseq, cst, bars, B_ * H_);
  tr_kernel<<<dim3(32, 32, 4), 256, 0, stream>>>(W, Wt);
  tr_kernel<<<dim3(32, 32, 4), 256, 0, stream>>>(U, Ut);
  prep_fc<<<16, 256, 0, stream>>>(lng, lnb, fcw, fcb, Bt, SA);

  for (int chunk = 0; chunk < T_ / TC_; ++chunk) {
    int t0 = chunk * TC_;
    convx<<<(B_ * TC_) / 4, 256, 0, stream>>>(x, xbf, t0);
    gemm_xz<<<dim3(32, (B_ * TC_) / 128), 256, 0, stream>>>(xbf, Wt, XZc);
    step_persist<<<256, 512, 0, stream>>>(t0, XZc, Ut, bias, hseq, cst,
                                          bars + chunk * 1024);
  }

  ln_fc_kernel<<<(B_ * T_) / 64, 256, 0, stream>>>(hseq + (size_t)B_ * H_, Bt, SA, out);
}

// Round 5
// 1601.073 us; speedup vs baseline: 2.2508x; 1.1264x over previous
//
#include <hip/hip_runtime.h>
#include <stdint.h>

typedef __bf16 bf16;
typedef __bf16 bf16x4 __attribute__((ext_vector_type(4)));
typedef __bf16 bf16x8 __attribute__((ext_vector_type(8)));
typedef float f32x4 __attribute__((ext_vector_type(4)));
typedef unsigned int u32x2 __attribute__((ext_vector_type(2)));

#define MFMA16x16x32(A, B, C) __builtin_amdgcn_mfma_f32_16x16x32_bf16((A), (B), (C), 0, 0, 0)

#define B_ 512
#define T_ 100
#define F_ 1024
#define H_ 1024

__device__ __forceinline__ float sigmoid_f(float x) { return 1.0f / (1.0f + __expf(-x)); }
__device__ __forceinline__ float b2bsqrt_f(float x) {
  float s = sqrtf(1.0f + fabsf(x)) - 1.0f;
  return x >= 0.0f ? s : -s;
}

// async global->LDS, 16B per lane; LDS dest = wave-uniform base + lane*16
__device__ __forceinline__ void glds16(const void* g, void* l) {
  __builtin_amdgcn_global_load_lds((const __attribute__((address_space(1))) void*)g,
                                   (__attribute__((address_space(3))) void*)l, 16, 0, 0);
}

// ---------------- zero-init h slot 0 and barrier counters ----------------
__global__ __launch_bounds__(256) void zero_init(bf16* __restrict__ h0,
                                                 unsigned* __restrict__ bars, int n) {
  int i = blockIdx.x * blockDim.x + threadIdx.x;
  if (i < n) h0[i] = (bf16)0.0f;
  if (i < 512) bars[i] = 0u;   // 8 groups x 64-dword stride
}

// ---------- transpose per gate: fp32 (1024 x 1024) -> bf16 transposed ----------
__global__ __launch_bounds__(256) void tr_kernel(const float* __restrict__ src,
                                                 bf16* __restrict__ dst) {
  __shared__ float tile[32][33];
  int g = blockIdx.z;
  int c0 = blockIdx.x * 32;
  int r0 = blockIdx.y * 32;
  const float* s = src + (size_t)g * 1024 * 1024;
  bf16* d = dst + (size_t)g * 1024 * 1024;
  int tx = threadIdx.x & 31, ty = threadIdx.x >> 5;
  #pragma unroll
  for (int i = 0; i < 32; i += 8)
    tile[ty + i][tx] = s[(size_t)(r0 + ty + i) * 1024 + c0 + tx];
  __syncthreads();
  #pragma unroll
  for (int i = 0; i < 32; i += 8)
    d[(size_t)(c0 + ty + i) * 1024 + r0 + tx] = (bf16)tile[tx][ty + i];
}

// ---------- cast ALL of x fp32 -> bf16, layout-preserving (row = b*100+t) ----------
__global__ __launch_bounds__(256) void convx_all(const float* __restrict__ x,
                                                 bf16* __restrict__ xbf) {
  size_t i = ((size_t)blockIdx.x * 256 + threadIdx.x) * 16;
  bf16x8 o0, o1;
  f32x4 f0 = *(const f32x4*)(x + i);
  f32x4 f1 = *(const f32x4*)(x + i + 4);
  f32x4 f2 = *(const f32x4*)(x + i + 8);
  f32x4 f3 = *(const f32x4*)(x + i + 12);
  #pragma unroll
  for (int j = 0; j < 4; ++j) {
    o0[j] = (bf16)f0[j]; o0[4 + j] = (bf16)f1[j];
    o1[j] = (bf16)f2[j]; o1[4 + j] = (bf16)f3[j];
  }
  *(bf16x8*)(xbf + i) = o0;
  *(bf16x8*)(xbf + i + 8) = o1;
}

// ---------- prep FC (unchanged) ----------
__global__ __launch_bounds__(256) void prep_fc(const float* __restrict__ lng,
                                               const float* __restrict__ lnb,
                                               const float* __restrict__ fcw,
                                               const float* __restrict__ fcb,
                                               bf16* __restrict__ Bt,
                                               float* __restrict__ SA) {
  __shared__ float red[2][256];
  int c = blockIdx.x;
  int tid = threadIdx.x;
  float pS = 0.f, pA = 0.f;
  #pragma unroll
  for (int j = 0; j < 4; ++j) {
    int h = j * 256 + tid;
    float v;
    if (c < 10) {
      float wv = fcw[h * 10 + c];
      v = lng[h] * wv;
      pS += v;
      pA += lnb[h] * wv;
    } else {
      v = (c == 10) ? 1.0f : 0.0f;
    }
    Bt[c * 1024 + h] = (bf16)v;
  }
  if (c < 10) {
    red[0][tid] = pS; red[1][tid] = pA;
    __syncthreads();
    for (int s = 128; s > 0; s >>= 1) {
      if (tid < s) { red[0][tid] += red[0][tid + s]; red[1][tid] += red[1][tid + s]; }
      __syncthreads();
    }
    if (tid == 0) { SA[c] = red[0][0]; SA[16 + c] = red[1][0] + fcb[c]; }
  }
}

// ---------------- xz GEMM over ALL T (m97-style): XZ = xbf @ Wt^T ----------------
// xbf (51200,1024) row lr = b*100+t; Wt (4096,1024) row n=g*1024+h. Out XZ (T,4,B,H) bf16.
__global__ __launch_bounds__(256) void gemm_xz(const bf16* __restrict__ X,
                                               const bf16* __restrict__ Wt,
                                               bf16* __restrict__ XZc) {
  __shared__ bf16 sA[128 * 32];
  __shared__ bf16 sB[128 * 32];
  const int tid = threadIdx.x;
  const int lane = tid & 63;
  const int w = tid >> 6;
  const int l16 = lane & 15;
  const int quad = lane >> 4;
  const int m0 = blockIdx.y * 128;
  const int n0 = blockIdx.x * 128;
  const int wm = (w >> 1) * 64;
  const int wn = (w & 1) * 64;
  const int rA = lane >> 2;
  const int gch = (lane & 3) ^ (rA & 3);

  f32x4 acc[4][4] = {};

  for (int kk = 0; kk < 1024; kk += 32) {
    #pragma unroll
    for (int j = 0; j < 2; ++j) {
      int r0 = (w * 2 + j) * 16;
      int r = r0 + rA;
      glds16(X + (size_t)(m0 + r) * 1024 + kk + gch * 8, sA + r0 * 32);
      glds16(Wt + (size_t)(n0 + r) * 1024 + kk + gch * 8, sB + r0 * 32);
    }
    __syncthreads();
    bf16x8 aF[4], bF[4];
    const int slot = quad ^ (l16 & 3);
    #pragma unroll
    for (int mt = 0; mt < 4; ++mt)
      aF[mt] = *(const bf16x8*)(sA + (wm + mt * 16 + l16) * 32 + slot * 8);
    #pragma unroll
    for (int nt = 0; nt < 4; ++nt)
      bF[nt] = *(const bf16x8*)(sB + (wn + nt * 16 + l16) * 32 + slot * 8);
    #pragma unroll
    for (int mt = 0; mt < 4; ++mt)
      #pragma unroll
      for (int nt = 0; nt < 4; ++nt)
        acc[mt][nt] = MFMA16x16x32(aF[mt], bF[nt], acc[mt][nt]);
    __syncthreads();
  }

  #pragma unroll
  for (int mt = 0; mt < 4; ++mt) {
    #pragma unroll
    for (int r = 0; r < 4; ++r) {
      unsigned lr = (unsigned)(m0 + wm + mt * 16 + quad * 4 + r);
      unsigned b = lr / 100u;
      unsigned t = lr - b * 100u;
      #pragma unroll
      for (int nt = 0; nt < 4; ++nt) {
        int n = n0 + wn + nt * 16 + l16;
        int g = n >> 10;
        int hh = n & 1023;
        XZc[((size_t)(t * 4 + g) * B_ + b) * H_ + hh] = (bf16)acc[mt][nt][r];
      }
    }
  }
}

// ------------- persistent recurrence v5: ALL 100 steps in one launch -------------
// 256 blocks x 512 thr, launch_bounds(512,1). bm = bid&7 (64 b-rows), hn = bid>>3 (32 h-cols).
// Grid = 8 INDEPENDENT groups of 32 blocks (group = bid&7); one 32-arrival counter per group.
// NO acquire fence: each hseq slot is written exactly once (sc0sc1 write-through, visible at
// mall before the counter increment via the vmcnt(0) drain in __syncthreads), and no thread
// reads a slot's lines before its group barrier -> no cache can hold a stale copy.
// Ut B-frags VGPR-resident for the WHOLE sequence; c-state lives in registers (no cst buffer).
// Per step: stage all 4 K-tiles (BK=256) via global_load_lds, counted vmcnt(12/8/4/0),
// one s_barrier per tile; Z-scratch union'd over the A-tiles.
__global__ __launch_bounds__(512, 1) void step_persist(
    const bf16* __restrict__ XZc,    // (T,4,B,H) bf16
    const bf16* __restrict__ Ut,     // (4096,1024): row n=g*1024+h, col k
    const float* __restrict__ bias,  // (4,H)
    bf16* __restrict__ hseq,         // slots 0..T
    unsigned* __restrict__ bar) {    // barrier state (512 dwords)
  __shared__ __align__(16) unsigned char smem[131072];  // 128 KB
  bf16* sA = (bf16*)smem;            // [4 tiles][64 rows][256 k] bf16
  float* sZf = (float*)smem;         // overlay: [8 waves][64*36] f32 (73728 B)

  const int tid = threadIdx.x;
  const int lane = tid & 63;
  const int w = tid >> 6;            // 0..7
  const int gate = w & 3;
  const int hf = w >> 2;             // K-half of each 256-tile
  const int l16 = lane & 15;
  const int quad = lane >> 4;
  const int bid = blockIdx.x;
  const int bm0 = (bid & 7) * 64;
  const int hn0 = (bid >> 3) * 32;
  unsigned* const grp = &bar[(bid & 7) * 64];  // group counter, 256B apart

  // ---- persistent B fragments (VGPR): bfr[nt][t*4+kh] over k = t*256+hf*128+kh*32+quad*8
  bf16x8 bfr[2][16];
  #pragma unroll
  for (int nt = 0; nt < 2; ++nt) {
    const bf16* up = Ut + (size_t)((gate << 10) + hn0 + nt * 16 + l16) * 1024 + hf * 128 + quad * 8;
    #pragma unroll
    for (int t = 0; t < 4; ++t)
      #pragma unroll
      for (int kh = 0; kh < 4; ++kh)
        bfr[nt][t * 4 + kh] = *(const bf16x8*)(up + t * 256 + kh * 32);
  }

  // ---- gate-phase mapping: row rr (0..63) x 4 h-cols; c-state in regs for all 100 steps
  const int rr = tid >> 3;
  const int cc = (tid & 7) * 4;
  const int gb = bm0 + rr;
  const int gh = hn0 + cc;
  f32x4 creg = {0.f, 0.f, 0.f, 0.f};
  f32x4 bs[4];
  #pragma unroll
  for (int g = 0; g < 4; ++g) bs[g] = *(const f32x4*)(bias + g * H_ + gh);

  // staging geometry: wave w, issue i stages rows w*8+i*2+{0,1} of a tile.
  // lane l -> row +(l>>5), 16B-chunk l&31. Swizzle: LDS[r][x] holds global chunk x^(r&15).
  const int srow = w * 8 + (lane >> 5);
  const int lch = lane & 31;

  // xz prefetch for step 0
  bf16x4 xzv[4];
  #pragma unroll
  for (int g = 0; g < 4; ++g)
    xzv[g] = *(const bf16x4*)(XZc + ((size_t)(0 * 4 + g) * B_ + gb) * H_ + gh);

  unsigned btarget = 0;

  for (int tt = 0; tt < T_; ++tt) {
    const bf16* hp = hseq + (size_t)tt * B_ * H_;
    bf16* hnx = hseq + (size_t)(tt + 1) * B_ * H_;

    // ---- prologue: stage all 4 K-tiles (16 glds16 per thread)
    #pragma unroll
    for (int t = 0; t < 4; ++t)
      #pragma unroll
      for (int i = 0; i < 4; ++i) {
        const int r = bm0 + srow + i * 2;
        glds16(hp + (size_t)r * 1024 + (size_t)(t * 32 + (lch ^ (r & 15))) * 8,
               smem + t * 32768 + (size_t)(w * 8 + i * 2) * 512);
      }

    f32x4 acc[4][2] = {};

    #pragma unroll
    for (int t = 0; t < 4; ++t) {
      if (t == 0)      asm volatile("s_waitcnt vmcnt(12)" ::: "memory");
      else if (t == 1) asm volatile("s_waitcnt vmcnt(8)" ::: "memory");
      else if (t == 2) asm volatile("s_waitcnt vmcnt(4)" ::: "memory");
      else             asm volatile("s_waitcnt vmcnt(0)" ::: "memory");
      __builtin_amdgcn_sched_barrier(0);
      __builtin_amdgcn_s_barrier();           // tile t staged by every wave
      __builtin_amdgcn_sched_barrier(0);
      #pragma unroll
      for (int kh = 0; kh < 4; ++kh) {
        const int S = hf * 16 + kh * 4 + quad;       // logical 16B chunk 0..31
        const int slot = S ^ l16;                    // XOR-swizzled read slot
        bf16x8 aF[4];
        #pragma unroll
        for (int mt = 0; mt < 4; ++mt)
          aF[mt] = *(const bf16x8*)(sA + (size_t)t * 16384 + (mt * 16 + l16) * 256 + slot * 8);
        #pragma unroll
        for (int mt = 0; mt < 4; ++mt) {
          acc[mt][0] = MFMA16x16x32(aF[mt], bfr[0][t * 4 + kh], acc[mt][0]);
          acc[mt][1] = MFMA16x16x32(aF[mt], bfr[1][t * 4 + kh], acc[mt][1]);
        }
      }
      __builtin_amdgcn_sched_barrier(0);
    }

    // ---- Z dump into overlay (all staging retired at vmcnt(0))
    #pragma unroll
    for (int mt = 0; mt < 4; ++mt)
      #pragma unroll
      for (int nt = 0; nt < 2; ++nt)
        #pragma unroll
        for (int r = 0; r < 4; ++r)
          sZf[w * 2304 + (mt * 16 + quad * 4 + r) * 36 + nt * 16 + l16] = acc[mt][nt][r];
    __syncthreads();

    // ---- gates: 4 h per thread; z = K-half0 + K-half1
    f32x4 z[4];
    #pragma unroll
    for (int g = 0; g < 4; ++g) {
      f32x4 za = *(const f32x4*)(sZf + g * 2304 + rr * 36 + cc);
      f32x4 zb = *(const f32x4*)(sZf + (g + 4) * 2304 + rr * 36 + cc);
      z[g] = za + zb;
    }
    bf16x4 hb;
    #pragma unroll
    for (int jj = 0; jj < 4; ++jj) {
      float I  = sigmoid_f(z[0][jj] + (float)xzv[0][jj] + bs[0][jj]);
      float Fg = sigmoid_f(z[1][jj] + (float)xzv[1][jj] + bs[1][jj]);
      float O  = sigmoid_f(z[2][jj] + (float)xzv[2][jj] + bs[2][jj]);
      float Ct = b2bsqrt_f(z[3][jj] + (float)xzv[3][jj] + bs[3][jj]);
      float c2 = Fg * creg[jj] + I * Ct;
      creg[jj] = c2;
      hb[jj] = (bf16)(O * b2bsqrt_f(c2));
    }
    // h store: sc0 sc1 write-through -> visible at mall (cross-XCD coherent point)
    {
      u32x2 hbu = __builtin_bit_cast(u32x2, hb);
      bf16* ha = hnx + (size_t)gb * H_ + gh;
      asm volatile("global_store_dwordx2 %0, %1, off sc0 sc1" :: "v"(ha), "v"(hbu) : "memory");
    }

    if (tt < T_ - 1) {
      // prefetch next step's xz while we wait at the barrier
      #pragma unroll
      for (int g = 0; g < 4; ++g)
        xzv[g] = *(const bf16x4*)(XZc + ((size_t)((tt + 1) * 4 + g) * B_ + gb) * H_ + gh);

      btarget += 32u;
      __syncthreads();                        // emits s_waitcnt vmcnt(0): h stores acked at mall
      if (tid == 0) {
        atomicAdd(grp, 1u);                   // fire-and-forget arrival
        unsigned spins = 0;
        while (__hip_atomic_load(grp, __ATOMIC_RELAXED, __HIP_MEMORY_SCOPE_AGENT)
               < btarget) {
          __builtin_amdgcn_s_sleep(1);
          if (++spins > (1u << 22)) break;    // bounded: fail loud, never hang
        }
        // NO acquire fence: h slot lines cannot be stale in any cache (written once,
        // never read pre-barrier); counter itself is read via the coherent atomic path.
      }
      __syncthreads();
    }
  }
}

// ------------- LN+FC as MFMA GEMM (unchanged) -------------
__global__ __launch_bounds__(256) void ln_fc_kernel(
    const bf16* __restrict__ hseq1, const bf16* __restrict__ Bt,
    const float* __restrict__ SA, float* __restrict__ out) {
  __shared__ bf16 sA[64 * 64];
  __shared__ bf16 sBt[16 * 1040];
  __shared__ float sLg[4][16 * 17];
  __shared__ float sSq[4][16];
  const int tid = threadIdx.x;
  const int lane = tid & 63;
  const int w = tid >> 6;
  const int l16 = lane & 15;
  const int quad = lane >> 4;
  const int m0 = blockIdx.x * 64;
  const int rL = lane >> 3;
  const int gch = (lane & 7) ^ rL;

  #pragma unroll
  for (int i = 0; i < 8; ++i) {
    int ch = tid + i * 256;
    int n = ch >> 7, k8 = ch & 127;
    *(bf16x8*)(sBt + n * 1040 + k8 * 8) = *(const bf16x8*)(Bt + n * 1024 + k8 * 8);
  }

  f32x4 acc = {};
  float sq = 0.f;

  for (int kk = 0; kk < 1024; kk += 64) {
    #pragma unroll
    for (int j = 0; j < 2; ++j) {
      int r0 = (w * 2 + j) * 8;
      int r = r0 + rL;
      glds16(hseq1 + (size_t)(m0 + r) * 1024 + kk + gch * 8, sA + r0 * 64);
    }
    __syncthreads();
    #pragma unroll
    for (int kh = 0; kh < 2; ++kh) {
      const int slot = (kh * 4 + quad) ^ (l16 & 7);
      bf16x8 aF = *(const bf16x8*)(sA + (w * 16 + l16) * 64 + slot * 8);
      bf16x8 bF = *(const bf16x8*)(sBt + l16 * 1040 + kk + kh * 32 + quad * 8);
      acc = MFMA16x16x32(aF, bF, acc);
      #pragma unroll
      for (int e = 0; e < 8; ++e) { float f = (float)aF[e]; sq += f * f; }
    }
    __syncthreads();
  }

  sq += __shfl_xor(sq, 16, 64);
  sq += __shfl_xor(sq, 32, 64);

  #pragma unroll
  for (int r = 0; r < 4; ++r)
    sLg[w][(quad * 4 + r) * 17 + l16] = acc[r];
  if (quad == 0) sSq[w][l16] = sq;
  __syncthreads();

  if (lane < 16) {
    int row = lane;
    float sum = sLg[w][row * 17 + 10];
    float ssq = sSq[w][row];
    float mu = sum * (1.0f / 1024.0f);
    float var = ssq * (1.0f / 1024.0f) - mu * mu;
    float rs = rsqrtf(var + 1e-5f);
    int rg = m0 + w * 16 + row;
    int t = rg >> 9, b = rg & 511;
    float* op = out + ((size_t)b * 100 + t) * 10;
    #pragma unroll
    for (int c = 0; c < 10; ++c)
      op[c] = rs * (sLg[w][row * 17 + c] - mu * SA[c]) + SA[16 + c];
  }
}

extern "C" void kernel_launch(void* const* d_in, const int* in_sizes, int n_in,
                              void* d_out, int out_size, void* d_ws, size_t ws_size,
                              hipStream_t stream) {
  (void)in_sizes; (void)n_in; (void)out_size; (void)ws_size;
  const float* x    = (const float*)d_in[0];
  const float* W    = (const float*)d_in[1];
  const float* U    = (const float*)d_in[2];
  const float* bias = (const float*)d_in[3];
  const float* lng  = (const float*)d_in[4];
  const float* lnb  = (const float*)d_in[5];
  const float* fcw  = (const float*)d_in[6];
  const float* fcb  = (const float*)d_in[7];
  float* out = (float*)d_out;

  char* ws = (char*)d_ws;
  size_t off = 0;
  bf16* Wt   = (bf16*)(ws + off); off += (size_t)4 * F_ * H_ * 2;           //   8.4 MB
  bf16* Ut   = (bf16*)(ws + off); off += (size_t)4 * H_ * H_ * 2;           //   8.4 MB
  bf16* XZc  = (bf16*)(ws + off); off += (size_t)T_ * 4 * B_ * H_ * 2;      // 419.4 MB
  bf16* hseq = (bf16*)(ws + off); off += (size_t)(T_ + 1) * B_ * H_ * 2;    // 105.9 MB
  bf16* xbf  = (bf16*)(ws + off); off += (size_t)B_ * T_ * F_ * 2;          // 104.9 MB
  bf16* Bt   = (bf16*)(ws + off); off += (size_t)16 * H_ * 2;               //  32 KB
  float* SA  = (float*)(ws + off); off += 32 * 4;
  unsigned* bars = (unsigned*)(ws + off); off += 512 * 4;
  // total ~647 MB (ws >= 838 MB per harness poison-fill WRITE_SIZE)

  zero_init<<<(B_ * H_ + 255) / 256, 256, 0, stream>>>(hseq, bars, B_ * H_);
  tr_kernel<<<dim3(32, 32, 4), 256, 0, stream>>>(W, Wt);
  tr_kernel<<<dim3(32, 32, 4), 256, 0, stream>>>(U, Ut);
  prep_fc<<<16, 256, 0, stream>>>(lng, lnb, fcw, fcb, Bt, SA);

  convx_all<<<(B_ * T_ * F_) / (256 * 16), 256, 0, stream>>>(x, xbf);
  gemm_xz<<<dim3(32, (B_ * T_) / 128), 256, 0, stream>>>(xbf, Wt, XZc);
  step_persist<<<256, 512, 0, stream>>>(XZc, Ut, bias, hseq, bars);

  ln_fc_kernel<<<(B_ * T_) / 64, 256, 0, stream>>>(hseq + (size_t)B_ * H_, Bt, SA, out);
}